// Round 7
// baseline (1725.311 us; speedup 1.0000x reference)
//
#include <hip/hip_runtime.h>
#include <cmath>

#define DI __device__ __forceinline__

constexpr int B_=2, S_=2048, E_=1024, H_=1344, NH_=4, DH_=336;
constexpr int BS_=B_*S_, H2_=2*H_;
constexpr int NG_=B_*NH_*S_;   // 16384

constexpr size_t N_X=(size_t)BS_*E_;
constexpr size_t N_WUP=(size_t)E_*H2_;
constexpr size_t N_WDN=(size_t)H_*E_;
constexpr size_t N_BSH=(size_t)BS_*H_;
constexpr size_t N_BSH2=(size_t)BS_*H2_;
constexpr size_t N_WH=5376, N_WG=16128, N_CK=4*H_;

// ---- ws layout (floats); identical to rounds 4-6 (passing) ----
constexpr size_t O_IGB = 64;
constexpr size_t O_LOGF= O_IGB + NG_;
constexpr size_t O_AB  = O_LOGF+ NG_;
constexpr size_t O_MB  = O_AB  + NG_;
constexpr size_t O_MTB = O_MB  + NG_;
constexpr size_t O_CK  = O_MTB + NG_;
constexpr size_t O_CB  = O_CK  + N_CK;
constexpr size_t O_WQ  = O_CB  + H_;
constexpr size_t O_WK  = O_WQ  + N_WH;
constexpr size_t O_WV  = O_WK  + N_WH;
constexpr size_t O_WIG = O_WV  + N_WH;
constexpr size_t O_BIG = O_WIG + N_WG;
constexpr size_t O_WFG = O_BIG + 16;
constexpr size_t O_BFG = O_WFG + N_WG;
constexpr size_t O_LNW = O_BFG + 16;
constexpr size_t O_SKP = O_LNW + H_;
constexpr size_t O_FX  = O_SKP + H_;
constexpr size_t O_FWUP= O_FX  + N_X;
constexpr size_t O_FWDN= O_FWUP+ N_WUP;
constexpr size_t O_XIN = O_FWDN+ N_WDN;
constexpr size_t O_ACT = O_XIN + N_BSH2;
constexpr size_t O_QB  = O_ACT + N_BSH;
constexpr size_t O_KB  = O_QB  + N_BSH;
constexpr size_t O_VB  = O_KB  + N_BSH;
constexpr size_t O_HOUT= O_VB  + N_BSH;

// khi/klo: [head][tt=t/16][dc=0..10][l=quad*16+lm][8] bf16
//   element = K[head][tt*16+lm][dc*32+quad*8+j]  (B-frag for 16x16x32)
constexpr size_t KSPLIT_SHORTS=(size_t)8*128*11*64*8;  // 5,767,168
// vTf: [head][tc=t/32][ntg=0..21][l][8] bf16; element = V[head][tc*32+quad*8+j][ntg*16+lm]
//   n==336 -> 1.0 (rowsum col), n>336 -> 0
constexpr size_t VT_SHORTS=(size_t)8*64*22*64*8;       // 5,767,168

typedef __attribute__((ext_vector_type(8))) short bf16x8;
typedef __attribute__((ext_vector_type(4))) float f32x4;

DI float bf2f(unsigned int u){union{unsigned int i;float f;}v;v.i=(u&0xffffu)<<16;return v.f;}
DI unsigned short f2bf(float f){union{float f;unsigned int i;}v;v.f=f;unsigned int x=v.i;
  return (unsigned short)((x+0x7fffu+((x>>16)&1u))>>16);}
DI float siluf(float x){return x/(1.f+expf(-x));}
DI float logsigf(float x){return (x>=0.f)?-log1pf(expf(-x)):x-log1pf(expf(x));}
DI void load4(const float* p, float* d){float4 v=*reinterpret_cast<const float4*>(p);
  d[0]=v.x;d[1]=v.y;d[2]=v.z;d[3]=v.w;}

// ---- dtype detect (fp32 proven in round 4; keep the guard) ----
__global__ __launch_bounds__(256) void detect_k(const unsigned short* __restrict__ xraw,
                                                int* __restrict__ flag){
  __shared__ int cnt_s;
  if(threadIdx.x==0) cnt_s=0;
  __syncthreads();
  int c=0;
  for(int i=threadIdx.x;i<2048;i+=256){
    const unsigned e=(xraw[i]>>7)&0xFFu;
    if(e>=0x90u) c++;
  }
  atomicAdd(&cnt_s,c);
  __syncthreads();
  if(threadIdx.x==0) *flag=(cnt_s>16)?0:1;
}

__global__ __launch_bounds__(256) void convert_k(const void* __restrict__ src,
                                                 float* __restrict__ dst,int n,
                                                 const int* __restrict__ flag){
  const int i=blockIdx.x*256+threadIdx.x;
  if(i>=n) return;
  if(*flag) dst[i]=bf2f(((const unsigned short*)src)[i]);
  else      dst[i]=((const float*)src)[i];
}

__global__ __launch_bounds__(256) void out_cast_k(const float* __restrict__ src,void* dst,
                                                  const int* __restrict__ flag){
  const int i=blockIdx.x*256+threadIdx.x;
  if(i>=(int)N_X) return;
  const float v=src[i];
  if(*flag) ((unsigned short*)dst)[i]=f2bf(v);
  else      ((float*)dst)[i]=v;
}

// ============================================================================
// 64x64x16 tiled fp32 GEMM, 4x4 register blocking (rounds 5-6, passing).
// ============================================================================
__global__ __launch_bounds__(256) void gemm_k(const float* __restrict__ A,
                                              const float* __restrict__ B,
                                              float* __restrict__ C,
                                              int M,int N,int Kd,int lda,int ldb,int ldc){
  __shared__ float As[16][68];
  __shared__ float Bs[16][68];
  const int t=threadIdx.x;
  const int bn=blockIdx.x*64, bm=blockIdx.y*64;
  const int tx=t&15, ty=t>>4;
  const int a_row=t>>2, a_k4=(t&3)*4;
  const int b_kk=t>>4, b_n4=(t&15)*4;
  float acc[4][4]={};
  for(int k0=0;k0<Kd;k0+=16){
    float av[4], bv[4];
    load4(&A[(size_t)(bm+a_row)*lda+k0+a_k4], av);
    load4(&B[(size_t)(k0+b_kk)*ldb+bn+b_n4], bv);
    __syncthreads();
#pragma unroll
    for(int i=0;i<4;i++) As[a_k4+i][a_row]=av[i];
    *reinterpret_cast<float4*>(&Bs[b_kk][b_n4])=make_float4(bv[0],bv[1],bv[2],bv[3]);
    __syncthreads();
#pragma unroll
    for(int kk=0;kk<16;kk++){
      float a4[4], b4[4];
      load4(&As[kk][ty*4], a4);
      load4(&Bs[kk][tx*4], b4);
#pragma unroll
      for(int i=0;i<4;i++)
#pragma unroll
        for(int j=0;j<4;j++) acc[i][j]+=a4[i]*b4[j];
    }
  }
#pragma unroll
  for(int i=0;i<4;i++)
#pragma unroll
    for(int j=0;j<4;j++)
      C[(size_t)(bm+ty*4+i)*ldc+bn+tx*4+j]=acc[i][j];
}

// ---- causal depthwise conv(K=4)+bias -> SiLU ----
__global__ __launch_bounds__(256) void conv_act_k(const float* __restrict__ xin,
                                                  const float* __restrict__ ck,
                                                  const float* __restrict__ cb,
                                                  float* __restrict__ act){
  const int i=blockIdx.x*256+threadIdx.x;
  if(i>=(int)N_BSH) return;
  const int bs=i/H_, h=i-bs*H_;
  const int b=bs/S_, s=bs-b*S_;
  float xc=cb[h];
#pragma unroll
  for(int w=0;w<4;w++){
    const int sr=s-3+w;
    if(sr>=0) xc+=xin[(size_t)(b*S_+sr)*H2_+h]*ck[w*H_+h];
  }
  act[(size_t)bs*H_+h]=siluf(xc);
}

// ---- headwise q/k/v ----
__global__ __launch_bounds__(256) void qkv_k(const float* __restrict__ act,
                                             const float* __restrict__ xin,
                                             const float* __restrict__ Wq,
                                             const float* __restrict__ Wk,
                                             const float* __restrict__ Wv,
                                             float* __restrict__ qb,float* __restrict__ kb,
                                             float* __restrict__ vb){
  const int i=blockIdx.x*256+threadIdx.x;
  if(i>=(int)N_BSH) return;
  const int bs=i/H_, h=i-bs*H_;
  const int b=bs/S_, s=bs-b*S_;
  const int ph=h>>2, o=h&3, base=ph*4;
  float q=0.f,k=0.f,v=0.f;
#pragma unroll
  for(int d=0;d<4;d++){
    const float a=act[(size_t)bs*H_+base+d];
    const float x=xin[(size_t)bs*H2_+base+d];
    q+=a*Wq[ph*16+d*4+o];
    k+=a*Wk[ph*16+d*4+o];
    v+=x*Wv[ph*16+d*4+o];
  }
  const int nh=h/DH_, dh=h-nh*DH_;
  const size_t off=((size_t)(b*NH_+nh)*S_+s)*DH_+dh;
  qb[off]=q; kb[off]=k; vb[off]=v;
}

// ---- gate pre-activations (round-4, passing) ----
__global__ __launch_bounds__(256) void gates_k(const float* __restrict__ qb,
                                               const float* __restrict__ kb,
                                               const float* __restrict__ vb,
                                               const float* __restrict__ Wig,
                                               const float* __restrict__ big,
                                               const float* __restrict__ Wfg,
                                               const float* __restrict__ bfg,
                                               float* __restrict__ igb,float* __restrict__ logfb){
  const int i=blockIdx.x*256+threadIdx.x;
  if(i>=BS_*NH_) return;
  const int bs=i>>2, n=i&3;
  const int b=bs/S_, s=bs-b*S_;
  float sig=0.f,sfg=0.f;
  for(int nh=0;nh<NH_;nh++){
    const size_t rb=((size_t)(b*NH_+nh)*S_+s)*DH_;
    for(int dh=0;dh<DH_;dh++){
      const int h=nh*DH_+dh;
      const float q=qb[rb+dh], k=kb[rb+dh], v=vb[rb+dh];
      sig+=q*Wig[h*4+n]+k*Wig[(H_+h)*4+n]+v*Wig[(2*H_+h)*4+n];
      sfg+=q*Wfg[h*4+n]+k*Wfg[(H_+h)*4+n]+v*Wfg[(2*H_+h)*4+n];
    }
  }
  const size_t off=(size_t)(b*NH_+n)*S_+s;
  igb[off]=sig+big[n];
  logfb[off]=logsigf(sfg+bfg[n]);
}

// ---- K prep: split fp32 K into hi/lo bf16, MFMA B-fragment tile layout ----
__global__ __launch_bounds__(256) void kprep_k(const float* __restrict__ kb,
                                               unsigned short* __restrict__ khi,
                                               unsigned short* __restrict__ klo){
  const int blk=blockIdx.x;                 // 8 heads * 128 t-tiles
  const int head=blk>>7, tt=blk&127;
  const size_t obase=(size_t)blk*11*512;
  for(int slot=threadIdx.x; slot<704; slot+=256){
    const int dc=slot>>6, ll=slot&63, quad=ll>>4, lm=ll&15;
    const int tg=tt*16+lm, dbase=dc*32+quad*8;
    float v[8];
    if(dbase<336){
      load4(&kb[((size_t)head*S_+tg)*DH_+dbase],v);
      load4(&kb[((size_t)head*S_+tg)*DH_+dbase+4],v+4);
    } else { for(int j=0;j<8;j++) v[j]=0.f; }
    unsigned short hi8[8], lo8[8];
#pragma unroll
    for(int j=0;j<8;j++){
      hi8[j]=f2bf(v[j]);
      lo8[j]=f2bf(v[j]-bf2f(hi8[j]));
    }
    const size_t o=obase+(size_t)(dc*64+ll)*8;
    uint4 ph, pl;
    ph.x=(unsigned)hi8[0]|((unsigned)hi8[1]<<16); ph.y=(unsigned)hi8[2]|((unsigned)hi8[3]<<16);
    ph.z=(unsigned)hi8[4]|((unsigned)hi8[5]<<16); ph.w=(unsigned)hi8[6]|((unsigned)hi8[7]<<16);
    pl.x=(unsigned)lo8[0]|((unsigned)lo8[1]<<16); pl.y=(unsigned)lo8[2]|((unsigned)lo8[3]<<16);
    pl.z=(unsigned)lo8[4]|((unsigned)lo8[5]<<16); pl.w=(unsigned)lo8[6]|((unsigned)lo8[7]<<16);
    *reinterpret_cast<uint4*>(&khi[o])=ph;
    *reinterpret_cast<uint4*>(&klo[o])=pl;
  }
}

// ---- V prep: V^T bf16 in MFMA B-fragment tile layout; col 336 = ones ----
__global__ __launch_bounds__(256) void vprep_k(const float* __restrict__ vb,
                                               unsigned short* __restrict__ vTf){
  const int blk=blockIdx.x;                 // 8 heads * 64 t-chunks
  const int head=blk>>6, tc=blk&63;
  const size_t obase=(size_t)blk*22*512;
  for(int slot=threadIdx.x; slot<1408; slot+=256){
    const int ntg=slot>>6, ll=slot&63, quad=ll>>4, lm=ll&15;
    const int n=ntg*16+lm, t0=tc*32+quad*8;
    unsigned short h8[8];
#pragma unroll
    for(int j=0;j<8;j++){
      float val;
      if(n<336)       val=vb[((size_t)head*S_+t0+j)*DH_+n];
      else if(n==336) val=1.f;
      else            val=0.f;
      h8[j]=f2bf(val);
    }
    uint4 pk;
    pk.x=(unsigned)h8[0]|((unsigned)h8[1]<<16); pk.y=(unsigned)h8[2]|((unsigned)h8[3]<<16);
    pk.z=(unsigned)h8[4]|((unsigned)h8[5]<<16); pk.w=(unsigned)h8[6]|((unsigned)h8[7]<<16);
    *reinterpret_cast<uint4*>(&vTf[obase+(size_t)(ntg*64+ll)*8])=pk;
  }
}

// ---- parallel per-head scan: c=cumsum(logf), a=ig-c, M=cummax(a), mt=c+M ----
__global__ __launch_bounds__(256) void scan_k(const float* __restrict__ igb,
                                              const float* __restrict__ logfb,
                                              float* __restrict__ ab,float* __restrict__ Mb,
                                              float* __restrict__ mtb){
  const int head=blockIdx.x, t=threadIdx.x;
  __shared__ float sh[256];
  const float* lf=logfb+(size_t)head*S_;
  const float* ig=igb+(size_t)head*S_;
  float lc[8];
  float run=0.f;
#pragma unroll
  for(int i=0;i<8;i++){ run+=lf[t*8+i]; lc[i]=run; }
  sh[t]=run;
  for(int st=1;st<256;st<<=1){
    __syncthreads();
    const float v=(t>=st)?sh[t-st]:0.f;
    __syncthreads();
    sh[t]+=v;
  }
  __syncthreads();
  const float off=(t==0)?0.f:sh[t-1];
  __syncthreads();
  float av[8],mv[8],cv[8];
  float mrun=-1e30f;
#pragma unroll
  for(int i=0;i<8;i++){
    cv[i]=off+lc[i];
    av[i]=ig[t*8+i]-cv[i];
    mrun=fmaxf(mrun,av[i]);
    mv[i]=mrun;
  }
  sh[t]=mrun;
  for(int st=1;st<256;st<<=1){
    __syncthreads();
    const float v=(t>=st)?sh[t-st]:-1e30f;
    __syncthreads();
    sh[t]=fmaxf(sh[t],v);
  }
  __syncthreads();
  const float moff=(t==0)?-1e30f:sh[t-1];
#pragma unroll
  for(int i=0;i<8;i++){
    const float Mi=fmaxf(moff,mv[i]);
    const size_t j=(size_t)head*S_+t*8+i;
    ab[j]=av[i]; Mb[j]=Mi; mtb[j]=cv[i]+Mi;
  }
}

// ============================================================================
// mLSTM v4 — fragment-direct. Block = (head, 32 s-rows); t-chunks of 32.
// K/V frags loaded straight from pre-tiled global (L2) into MFMA operands —
// no staging LDS, no conversion, 1 barrier/chunk (double-buffered Sc).
// QK: 3 split chains (qh*kh + ql*kh + qh*kl). Rowsum via ones-col (n=336).
// Epilogue: shuffle-reduced groupnorm, no LDS O round-trip.
// ============================================================================
__global__ __launch_bounds__(256) void mlstm_k(
    const float* __restrict__ qb, const unsigned short* __restrict__ khi,
    const unsigned short* __restrict__ klo, const unsigned short* __restrict__ vTf,
    const float* __restrict__ ab, const float* __restrict__ Mb, const float* __restrict__ mtb,
    const float* __restrict__ lnw, float* __restrict__ hout){
  const int head=blockIdx.y, bI=head>>2, nh=head&3;
  const int s0=(gridDim.x-1-blockIdx.x)*32;   // heavy blocks first
  const int t=threadIdx.x, w=t>>6, l=t&63;
  const int st=w>>1, tt=w&1, lm=l&15, quad=l>>4;

  __shared__ short Sc[2][32][40];             // dbuf, +8 pad breaks b128 conflicts
  __shared__ float M_l[32], inv_s[32];
  __shared__ float redS[32][2][2];
  __shared__ float mu_s[32], rs_s[32];

  const size_t hb=(size_t)head*S_;
  // ---- persistent Q fragments (split hi/lo bf16), 11 d-chunks ----
  bf16x8 qh[11], ql[11];
  {
    const float* qrow=qb+(hb+s0+st*16+lm)*DH_;
#pragma unroll
    for(int dc=0;dc<11;dc++){
      const int dbase=dc*32+quad*8;
      float v[8];
      if(dbase<336){ load4(qrow+dbase,v); load4(qrow+dbase+4,v+4); }
      else { for(int j=0;j<8;j++) v[j]=0.f; }
#pragma unroll
      for(int j=0;j<8;j++){
        const unsigned short h=f2bf(v[j]);
        qh[dc][j]=(short)h;
        ql[dc][j]=(short)f2bf(v[j]-bf2f(h));
      }
    }
  }
  if(t<32) M_l[t]=Mb[hb+s0+t];
  f32x4 accO[11];
#pragma unroll
  for(int n=0;n<11;n++) accO[n]={0.f,0.f,0.f,0.f};
  __syncthreads();

  const float scale=0.05455447256f;           // 336^-0.5
  const int nch=(s0>>5)+1;

  for(int tc=0;tc<nch;tc++){
    const int t0=tc<<5;
    // ---- QK: B-frags direct from global (pipelined with MFMAs) ----
    const size_t kb0=(((size_t)head*128+(size_t)(tc*2+tt))*11)*512+(size_t)l*8;
    f32x4 aq0={0,0,0,0}, aq1={0,0,0,0}, aq2={0,0,0,0};
#pragma unroll
    for(int dc=0;dc<11;dc++){
      const bf16x8 kh=*reinterpret_cast<const bf16x8*>(&khi[kb0+(size_t)dc*512]);
      const bf16x8 kl=*reinterpret_cast<const bf16x8*>(&klo[kb0+(size_t)dc*512]);
      aq0=__builtin_amdgcn_mfma_f32_16x16x32_bf16(qh[dc],kh,aq0,0,0,0);
      aq1=__builtin_amdgcn_mfma_f32_16x16x32_bf16(ql[dc],kh,aq1,0,0,0);
      aq2=__builtin_amdgcn_mfma_f32_16x16x32_bf16(qh[dc],kl,aq2,0,0,0);
    }
    // ---- mask/exp -> Sc bf16 (dbuf) ----
    const float al=ab[hb+t0+tt*16+lm];
    const int tg=t0+tt*16+lm, buf=tc&1;
#pragma unroll
    for(int r=0;r<4;r++){
      const int srow=st*16+quad*4+r;
      const float qk=aq0[r]+aq1[r]+aq2[r];
      const float e=fminf(al-M_l[srow],0.f);
      const float msk=(tg<=s0+srow)?1.f:0.f;
      Sc[buf][srow][tt*16+lm]=(short)f2bf(msk*(qk*scale*expf(e)));
    }
    __syncthreads();                          // the only barrier per chunk
    // ---- PV: A-frag from LDS, B-frags direct from global ----
    const bf16x8 scf=*reinterpret_cast<const bf16x8*>(&Sc[buf][st*16+lm][quad*8]);
    const size_t vb0=(((size_t)head*64+tc)*22+(size_t)(tt*11))*512+(size_t)l*8;
#pragma unroll
    for(int nt=0;nt<11;nt++){
      const bf16x8 vf=*reinterpret_cast<const bf16x8*>(&vTf[vb0+(size_t)nt*512]);
      accO[nt]=__builtin_amdgcn_mfma_f32_16x16x32_bf16(scf,vf,accO[nt],0,0,0);
    }
  }

  // ---- epilogue: n-normalizer + shuffle-reduced groupnorm ----
  if(tt==1 && lm==0){                         // col 336 = rowsum
#pragma unroll
    for(int r=0;r<4;r++){
      const int srow=st*16+quad*4+r;
      const float mt=mtb[hb+s0+srow];
      const float nn=fmaxf(fabsf(accO[10][r]), expf(fminf(fmaxf(-mt,-60.f),60.f)));
      inv_s[srow]=1.f/(nn+1e-6f);
    }
  }
  float s1[4]={}, s2[4]={};
  const int ntmax=(tt==1 && lm==0)?10:11;     // exclude rowsum col from stats
#pragma unroll
  for(int r=0;r<4;r++){
    for(int nt=0;nt<ntmax;nt++){ const float v=accO[nt][r]; s1[r]+=v; s2[r]+=v*v; }
#pragma unroll
    for(int m=1;m<16;m<<=1){ s1[r]+=__shfl_xor(s1[r],m); s2[r]+=__shfl_xor(s2[r],m); }
  }
  if(lm==0){
#pragma unroll
    for(int r=0;r<4;r++){
      const int srow=st*16+quad*4+r;
      redS[srow][tt][0]=s1[r]; redS[srow][tt][1]=s2[r];
    }
  }
  __syncthreads();
  if(t<32){
    const float inv=inv_s[t];
    const float rs1=(redS[t][0][0]+redS[t][1][0])*inv;
    const float rs2=(redS[t][0][1]+redS[t][1][1])*inv*inv;
    const float mu=rs1/336.f;
    const float var=rs2/336.f-mu*mu;
    mu_s[t]=mu;
    rs_s[t]=rsqrtf(fmaxf(var,0.f)+1e-5f);
  }
  __syncthreads();
#pragma unroll
  for(int r=0;r<4;r++){
    const int srow=st*16+quad*4+r;
    const float inv=inv_s[srow], mu=mu_s[srow], rs=rs_s[srow];
    float* orow=hout+((size_t)(bI*S_+s0+srow))*H_+nh*DH_;
#pragma unroll
    for(int nt=0;nt<11;nt++){
      const int col=tt*176+nt*16+lm;
      if(col<336) orow[col]=(accO[nt][r]*inv-mu)*rs*lnw[nh*DH_+col];
    }
  }
}

// ---- h_state = (h_out + skip*act) * silu(z) ----
__global__ __launch_bounds__(256) void hstate_k(const float* __restrict__ hout,
                                                const float* __restrict__ act,
                                                const float* __restrict__ xin,
                                                const float* __restrict__ skip,
                                                float* __restrict__ hs){
  const int i=blockIdx.x*256+threadIdx.x;
  if(i>=(int)N_BSH) return;
  const int bs=i/H_, h=i-bs*H_;
  const float z=xin[(size_t)bs*H2_+H_+h];
  hs[(size_t)bs*H_+h]=(hout[(size_t)bs*H_+h]+skip[h]*act[(size_t)bs*H_+h])*siluf(z);
}

// ============================================================================
extern "C" void kernel_launch(void* const* d_in, const int* in_sizes, int n_in,
                              void* d_out, int out_size, void* d_ws, size_t ws_size,
                              hipStream_t stream){
  float* ws=(float*)d_ws;
  int* flag=(int*)ws;

  float* igb  = ws+O_IGB;
  float* logfb= ws+O_LOGF;
  float* ab   = ws+O_AB;
  float* Mbuf = ws+O_MB;
  float* mtb  = ws+O_MTB;
  float* f_ck = ws+O_CK;
  float* f_cb = ws+O_CB;
  float* f_wq = ws+O_WQ;
  float* f_wk = ws+O_WK;
  float* f_wv = ws+O_WV;
  float* f_wig= ws+O_WIG;
  float* f_big= ws+O_BIG;
  float* f_wfg= ws+O_WFG;
  float* f_bfg= ws+O_BFG;
  float* f_lnw= ws+O_LNW;
  float* f_skp= ws+O_SKP;
  float* f_x  = ws+O_FX;
  float* f_wup= ws+O_FWUP;
  float* f_wdn= ws+O_FWDN;
  float* xin  = ws+O_XIN;
  float* act  = ws+O_ACT;
  float* qb   = ws+O_QB;
  float* kb   = ws+O_KB;
  float* vb   = ws+O_VB;
  float* hout = ws+O_HOUT;
  float* hs   = qb;                            // alias: q dead after mlstm_k
  float* outf = f_x;                           // alias: khi region dead after mlstm_k
  // khi+klo alias f_x+f_wup (23.1MB <= 27.8MB, dead after up-gemm; overwritten
  // by outf only after mlstm). vTf aliases kb (dead after gates_k+kprep_k).
  unsigned short* khi=(unsigned short*)f_x;
  unsigned short* klo=khi+KSPLIT_SHORTS;
  unsigned short* vTf=(unsigned short*)kb;

  detect_k<<<1,256,0,stream>>>((const unsigned short*)d_in[0],flag);
  auto cvt=[&](int idx,float* dst,size_t n){
    convert_k<<<(int)((n+255)/256),256,0,stream>>>(d_in[idx],dst,(int)n,flag);
  };
  cvt(0,f_x,N_X);   cvt(1,f_wup,N_WUP); cvt(2,f_ck,N_CK);  cvt(3,f_cb,H_);
  cvt(4,f_wq,N_WH); cvt(5,f_wk,N_WH);   cvt(6,f_wv,N_WH);  cvt(7,f_wig,N_WG);
  cvt(8,f_big,4);   cvt(9,f_wfg,N_WG);  cvt(10,f_bfg,4);   cvt(11,f_lnw,H_);
  cvt(12,f_skp,H_); cvt(13,f_wdn,N_WDN);

  gemm_k<<<dim3(H2_/64,BS_/64),256,0,stream>>>(f_x,f_wup,xin,BS_,H2_,E_,E_,H2_,H2_);
  conv_act_k<<<(int)((N_BSH+255)/256),256,0,stream>>>(xin,f_ck,f_cb,act);
  qkv_k<<<(int)((N_BSH+255)/256),256,0,stream>>>(act,xin,f_wq,f_wk,f_wv,qb,kb,vb);
  gates_k<<<(BS_*NH_+255)/256,256,0,stream>>>(qb,kb,vb,f_wig,f_big,f_wfg,f_bfg,igb,logfb);
  kprep_k<<<8*128,256,0,stream>>>(kb,khi,klo);          // after gates (reads kb)
  vprep_k<<<8*64,256,0,stream>>>(vb,vTf);               // writes over kb region
  scan_k<<<B_*NH_,256,0,stream>>>(igb,logfb,ab,Mbuf,mtb);
  mlstm_k<<<dim3(S_/32,B_*NH_),256,0,stream>>>(qb,khi,klo,vTf,ab,Mbuf,mtb,f_lnw,hout);
  hstate_k<<<(int)((N_BSH+255)/256),256,0,stream>>>(hout,act,xin,f_skp,hs);
  gemm_k<<<dim3(E_/64,BS_/64),256,0,stream>>>(hs,f_wdn,outf,BS_,E_,H_,H_,E_,E_);
  out_cast_k<<<(int)((N_X+255)/256),256,0,stream>>>(outf,d_out,flag);
}

// Round 8
// 1521.204 us; speedup vs baseline: 1.1342x; 1.1342x over previous
//
#include <hip/hip_runtime.h>
#include <cmath>

#define DI __device__ __forceinline__

constexpr int B_=2, S_=2048, E_=1024, H_=1344, NH_=4, DH_=336;
constexpr int BS_=B_*S_, H2_=2*H_;
constexpr int NG_=B_*NH_*S_;   // 16384
constexpr int TS_=4;           // split-K t-segments

constexpr size_t N_X=(size_t)BS_*E_;
constexpr size_t N_WUP=(size_t)E_*H2_;
constexpr size_t N_WDN=(size_t)H_*E_;
constexpr size_t N_BSH=(size_t)BS_*H_;
constexpr size_t N_BSH2=(size_t)BS_*H2_;
constexpr size_t N_WH=5376, N_WG=16128, N_CK=4*H_;

// ---- ws layout (floats); identical to rounds 4-7 (passing) ----
constexpr size_t O_IGB = 64;
constexpr size_t O_LOGF= O_IGB + NG_;
constexpr size_t O_AB  = O_LOGF+ NG_;
constexpr size_t O_MB  = O_AB  + NG_;
constexpr size_t O_MTB = O_MB  + NG_;
constexpr size_t O_CK  = O_MTB + NG_;
constexpr size_t O_CB  = O_CK  + N_CK;
constexpr size_t O_WQ  = O_CB  + H_;
constexpr size_t O_WK  = O_WQ  + N_WH;
constexpr size_t O_WV  = O_WK  + N_WH;
constexpr size_t O_WIG = O_WV  + N_WH;
constexpr size_t O_BIG = O_WIG + N_WG;
constexpr size_t O_WFG = O_BIG + 16;
constexpr size_t O_BFG = O_WFG + N_WG;
constexpr size_t O_LNW = O_BFG + 16;
constexpr size_t O_SKP = O_LNW + H_;
constexpr size_t O_FX  = O_SKP + H_;
constexpr size_t O_FWUP= O_FX  + N_X;
constexpr size_t O_FWDN= O_FWUP+ N_WUP;
constexpr size_t O_XIN = O_FWDN+ N_WDN;
constexpr size_t O_ACT = O_XIN + N_BSH2;
constexpr size_t O_QB  = O_ACT + N_BSH;
constexpr size_t O_KB  = O_QB  + N_BSH;
constexpr size_t O_VB  = O_KB  + N_BSH;
constexpr size_t O_HOUT= O_VB  + N_BSH;

// khi/klo: [head][tt=t/16][dc=0..10][l=quad*16+lm][8] bf16 (B-frag 16x16x32)
constexpr size_t KSPLIT_SHORTS=(size_t)8*128*11*64*8;  // 5,767,168
// vTf: [head][tc][ntg=0..21][l][8] bf16; n==336 -> 1.0 (rowsum col), n>336 -> 0
constexpr size_t VT_SHORTS=(size_t)8*64*22*64*8;       // 5,767,168
// part: [head][sblk][srow(32)][336] fp32  == N_BSH floats exactly (aliases vb)
// rsum: [head][sblk][srow(32)]  fp32  == NG_ floats (aliases igb)

typedef __attribute__((ext_vector_type(8))) short bf16x8;
typedef __attribute__((ext_vector_type(4))) float f32x4;

DI float bf2f(unsigned int u){union{unsigned int i;float f;}v;v.i=(u&0xffffu)<<16;return v.f;}
DI unsigned short f2bf(float f){union{float f;unsigned int i;}v;v.f=f;unsigned int x=v.i;
  return (unsigned short)((x+0x7fffu+((x>>16)&1u))>>16);}
DI float siluf(float x){return x/(1.f+expf(-x));}
DI float logsigf(float x){return (x>=0.f)?-log1pf(expf(-x)):x-log1pf(expf(x));}
DI void load4(const float* p, float* d){float4 v=*reinterpret_cast<const float4*>(p);
  d[0]=v.x;d[1]=v.y;d[2]=v.z;d[3]=v.w;}

// ---- dtype detect (fp32 proven in round 4; keep the guard) ----
__global__ __launch_bounds__(256) void detect_k(const unsigned short* __restrict__ xraw,
                                                int* __restrict__ flag){
  __shared__ int cnt_s;
  if(threadIdx.x==0) cnt_s=0;
  __syncthreads();
  int c=0;
  for(int i=threadIdx.x;i<2048;i+=256){
    const unsigned e=(xraw[i]>>7)&0xFFu;
    if(e>=0x90u) c++;
  }
  atomicAdd(&cnt_s,c);
  __syncthreads();
  if(threadIdx.x==0) *flag=(cnt_s>16)?0:1;
}

__global__ __launch_bounds__(256) void convert_k(const void* __restrict__ src,
                                                 float* __restrict__ dst,int n,
                                                 const int* __restrict__ flag){
  const int i=blockIdx.x*256+threadIdx.x;
  if(i>=n) return;
  if(*flag) dst[i]=bf2f(((const unsigned short*)src)[i]);
  else      dst[i]=((const float*)src)[i];
}

__global__ __launch_bounds__(256) void out_cast_k(const float* __restrict__ src,void* dst,
                                                  const int* __restrict__ flag){
  const int i=blockIdx.x*256+threadIdx.x;
  if(i>=(int)N_X) return;
  const float v=src[i];
  if(*flag) ((unsigned short*)dst)[i]=f2bf(v);
  else      ((float*)dst)[i]=v;
}

// ============================================================================
// 64x64x16 tiled fp32 GEMM, 4x4 register blocking (rounds 5-7, passing).
// ============================================================================
__global__ __launch_bounds__(256) void gemm_k(const float* __restrict__ A,
                                              const float* __restrict__ B,
                                              float* __restrict__ C,
                                              int M,int N,int Kd,int lda,int ldb,int ldc){
  __shared__ float As[16][68];
  __shared__ float Bs[16][68];
  const int t=threadIdx.x;
  const int bn=blockIdx.x*64, bm=blockIdx.y*64;
  const int tx=t&15, ty=t>>4;
  const int a_row=t>>2, a_k4=(t&3)*4;
  const int b_kk=t>>4, b_n4=(t&15)*4;
  float acc[4][4]={};
  for(int k0=0;k0<Kd;k0+=16){
    float av[4], bv[4];
    load4(&A[(size_t)(bm+a_row)*lda+k0+a_k4], av);
    load4(&B[(size_t)(k0+b_kk)*ldb+bn+b_n4], bv);
    __syncthreads();
#pragma unroll
    for(int i=0;i<4;i++) As[a_k4+i][a_row]=av[i];
    *reinterpret_cast<float4*>(&Bs[b_kk][b_n4])=make_float4(bv[0],bv[1],bv[2],bv[3]);
    __syncthreads();
#pragma unroll
    for(int kk=0;kk<16;kk++){
      float a4[4], b4[4];
      load4(&As[kk][ty*4], a4);
      load4(&Bs[kk][tx*4], b4);
#pragma unroll
      for(int i=0;i<4;i++)
#pragma unroll
        for(int j=0;j<4;j++) acc[i][j]+=a4[i]*b4[j];
    }
  }
#pragma unroll
  for(int i=0;i<4;i++)
#pragma unroll
    for(int j=0;j<4;j++)
      C[(size_t)(bm+ty*4+i)*ldc+bn+tx*4+j]=acc[i][j];
}

// ---- causal depthwise conv(K=4)+bias -> SiLU ----
__global__ __launch_bounds__(256) void conv_act_k(const float* __restrict__ xin,
                                                  const float* __restrict__ ck,
                                                  const float* __restrict__ cb,
                                                  float* __restrict__ act){
  const int i=blockIdx.x*256+threadIdx.x;
  if(i>=(int)N_BSH) return;
  const int bs=i/H_, h=i-bs*H_;
  const int b=bs/S_, s=bs-b*S_;
  float xc=cb[h];
#pragma unroll
  for(int w=0;w<4;w++){
    const int sr=s-3+w;
    if(sr>=0) xc+=xin[(size_t)(b*S_+sr)*H2_+h]*ck[w*H_+h];
  }
  act[(size_t)bs*H_+h]=siluf(xc);
}

// ---- headwise q/k/v ----
__global__ __launch_bounds__(256) void qkv_k(const float* __restrict__ act,
                                             const float* __restrict__ xin,
                                             const float* __restrict__ Wq,
                                             const float* __restrict__ Wk,
                                             const float* __restrict__ Wv,
                                             float* __restrict__ qb,float* __restrict__ kb,
                                             float* __restrict__ vb){
  const int i=blockIdx.x*256+threadIdx.x;
  if(i>=(int)N_BSH) return;
  const int bs=i/H_, h=i-bs*H_;
  const int b=bs/S_, s=bs-b*S_;
  const int ph=h>>2, o=h&3, base=ph*4;
  float q=0.f,k=0.f,v=0.f;
#pragma unroll
  for(int d=0;d<4;d++){
    const float a=act[(size_t)bs*H_+base+d];
    const float x=xin[(size_t)bs*H2_+base+d];
    q+=a*Wq[ph*16+d*4+o];
    k+=a*Wk[ph*16+d*4+o];
    v+=x*Wv[ph*16+d*4+o];
  }
  const int nh=h/DH_, dh=h-nh*DH_;
  const size_t off=((size_t)(b*NH_+nh)*S_+s)*DH_+dh;
  qb[off]=q; kb[off]=k; vb[off]=v;
}

// ---- gate pre-activations (round-4, passing) ----
__global__ __launch_bounds__(256) void gates_k(const float* __restrict__ qb,
                                               const float* __restrict__ kb,
                                               const float* __restrict__ vb,
                                               const float* __restrict__ Wig,
                                               const float* __restrict__ big,
                                               const float* __restrict__ Wfg,
                                               const float* __restrict__ bfg,
                                               float* __restrict__ igb,float* __restrict__ logfb){
  const int i=blockIdx.x*256+threadIdx.x;
  if(i>=BS_*NH_) return;
  const int bs=i>>2, n=i&3;
  const int b=bs/S_, s=bs-b*S_;
  float sig=0.f,sfg=0.f;
  for(int nh=0;nh<NH_;nh++){
    const size_t rb=((size_t)(b*NH_+nh)*S_+s)*DH_;
    for(int dh=0;dh<DH_;dh++){
      const int h=nh*DH_+dh;
      const float q=qb[rb+dh], k=kb[rb+dh], v=vb[rb+dh];
      sig+=q*Wig[h*4+n]+k*Wig[(H_+h)*4+n]+v*Wig[(2*H_+h)*4+n];
      sfg+=q*Wfg[h*4+n]+k*Wfg[(H_+h)*4+n]+v*Wfg[(2*H_+h)*4+n];
    }
  }
  const size_t off=(size_t)(b*NH_+n)*S_+s;
  igb[off]=sig+big[n];
  logfb[off]=logsigf(sfg+bfg[n]);
}

// ---- K prep: split fp32 K into hi/lo bf16, MFMA B-fragment tile layout ----
__global__ __launch_bounds__(256) void kprep_k(const float* __restrict__ kb,
                                               unsigned short* __restrict__ khi,
                                               unsigned short* __restrict__ klo){
  const int blk=blockIdx.x;                 // 8 heads * 128 t-tiles
  const int head=blk>>7, tt=blk&127;
  const size_t obase=(size_t)blk*11*512;
  for(int slot=threadIdx.x; slot<704; slot+=256){
    const int dc=slot>>6, ll=slot&63, quad=ll>>4, lm=ll&15;
    const int tg=tt*16+lm, dbase=dc*32+quad*8;
    float v[8];
    if(dbase<336){
      load4(&kb[((size_t)head*S_+tg)*DH_+dbase],v);
      load4(&kb[((size_t)head*S_+tg)*DH_+dbase+4],v+4);
    } else { for(int j=0;j<8;j++) v[j]=0.f; }
    unsigned short hi8[8], lo8[8];
#pragma unroll
    for(int j=0;j<8;j++){
      hi8[j]=f2bf(v[j]);
      lo8[j]=f2bf(v[j]-bf2f(hi8[j]));
    }
    const size_t o=obase+(size_t)(dc*64+ll)*8;
    uint4 ph, pl;
    ph.x=(unsigned)hi8[0]|((unsigned)hi8[1]<<16); ph.y=(unsigned)hi8[2]|((unsigned)hi8[3]<<16);
    ph.z=(unsigned)hi8[4]|((unsigned)hi8[5]<<16); ph.w=(unsigned)hi8[6]|((unsigned)hi8[7]<<16);
    pl.x=(unsigned)lo8[0]|((unsigned)lo8[1]<<16); pl.y=(unsigned)lo8[2]|((unsigned)lo8[3]<<16);
    pl.z=(unsigned)lo8[4]|((unsigned)lo8[5]<<16); pl.w=(unsigned)lo8[6]|((unsigned)lo8[7]<<16);
    *reinterpret_cast<uint4*>(&khi[o])=ph;
    *reinterpret_cast<uint4*>(&klo[o])=pl;
  }
}

// ---- V prep: V^T bf16 in MFMA B-fragment tile layout; col 336 = ones ----
__global__ __launch_bounds__(256) void vprep_k(const float* __restrict__ vb,
                                               unsigned short* __restrict__ vTf){
  const int blk=blockIdx.x;                 // 8 heads * 64 t-chunks
  const int head=blk>>6, tc=blk&63;
  const size_t obase=(size_t)blk*22*512;
  for(int slot=threadIdx.x; slot<1408; slot+=256){
    const int ntg=slot>>6, ll=slot&63, quad=ll>>4, lm=ll&15;
    const int n=ntg*16+lm, t0=tc*32+quad*8;
    unsigned short h8[8];
#pragma unroll
    for(int j=0;j<8;j++){
      float val;
      if(n<336)       val=vb[((size_t)head*S_+t0+j)*DH_+n];
      else if(n==336) val=1.f;
      else            val=0.f;
      h8[j]=f2bf(val);
    }
    uint4 pk;
    pk.x=(unsigned)h8[0]|((unsigned)h8[1]<<16); pk.y=(unsigned)h8[2]|((unsigned)h8[3]<<16);
    pk.z=(unsigned)h8[4]|((unsigned)h8[5]<<16); pk.w=(unsigned)h8[6]|((unsigned)h8[7]<<16);
    *reinterpret_cast<uint4*>(&vTf[obase+(size_t)(ntg*64+ll)*8])=pk;
  }
}

// ---- parallel per-head scan (round-7, passing) ----
__global__ __launch_bounds__(256) void scan_k(const float* __restrict__ igb,
                                              const float* __restrict__ logfb,
                                              float* __restrict__ ab,float* __restrict__ Mb,
                                              float* __restrict__ mtb){
  const int head=blockIdx.x, t=threadIdx.x;
  __shared__ float sh[256];
  const float* lf=logfb+(size_t)head*S_;
  const float* ig=igb+(size_t)head*S_;
  float lc[8];
  float run=0.f;
#pragma unroll
  for(int i=0;i<8;i++){ run+=lf[t*8+i]; lc[i]=run; }
  sh[t]=run;
  for(int st=1;st<256;st<<=1){
    __syncthreads();
    const float v=(t>=st)?sh[t-st]:0.f;
    __syncthreads();
    sh[t]+=v;
  }
  __syncthreads();
  const float off=(t==0)?0.f:sh[t-1];
  __syncthreads();
  float av[8],mv[8],cv[8];
  float mrun=-1e30f;
#pragma unroll
  for(int i=0;i<8;i++){
    cv[i]=off+lc[i];
    av[i]=ig[t*8+i]-cv[i];
    mrun=fmaxf(mrun,av[i]);
    mv[i]=mrun;
  }
  sh[t]=mrun;
  for(int st=1;st<256;st<<=1){
    __syncthreads();
    const float v=(t>=st)?sh[t-st]:-1e30f;
    __syncthreads();
    sh[t]=fmaxf(sh[t],v);
  }
  __syncthreads();
  const float moff=(t==0)?-1e30f:sh[t-1];
#pragma unroll
  for(int i=0;i<8;i++){
    const float Mi=fmaxf(moff,mv[i]);
    const size_t j=(size_t)head*S_+t*8+i;
    ab[j]=av[i]; Mb[j]=Mi; mtb[j]=cv[i]+Mi;
  }
}

// ============================================================================
// mLSTM v5 — fragment-direct + split-K over t. Block = (sblk, head, seg);
// seg handles chunks c = seg, seg+4, ... < nch. Partial O accumulated in
// registers, atomically added to part/rsum. 2048 blocks -> real occupancy.
// ============================================================================
__global__ __launch_bounds__(256) void mlstm_k(
    const float* __restrict__ qb, const unsigned short* __restrict__ khi,
    const unsigned short* __restrict__ klo, const unsigned short* __restrict__ vTf,
    const float* __restrict__ ab, const float* __restrict__ Mb,
    float* __restrict__ part, float* __restrict__ rsum){
  const int head=blockIdx.y, seg=blockIdx.z;
  const int sblk=gridDim.x-1-blockIdx.x;      // heavy blocks first
  const int s0=sblk*32;
  const int nch=(s0>>5)+1;
  if(seg>=nch) return;
  const int t=threadIdx.x, w=t>>6, l=t&63;
  const int st=w>>1, tt=w&1, lm=l&15, quad=l>>4;

  __shared__ short Sc[2][32][40];             // dbuf; +8 pad
  __shared__ float M_l[32];

  const size_t hb=(size_t)head*S_;
  // ---- persistent Q fragments (split hi/lo bf16), 11 d-chunks ----
  bf16x8 qh[11], ql[11];
  {
    const float* qrow=qb+(hb+s0+st*16+lm)*DH_;
#pragma unroll
    for(int dc=0;dc<11;dc++){
      const int dbase=dc*32+quad*8;
      float v[8];
      if(dbase<336){ load4(qrow+dbase,v); load4(qrow+dbase+4,v+4); }
      else { for(int j=0;j<8;j++) v[j]=0.f; }
#pragma unroll
      for(int j=0;j<8;j++){
        const unsigned short h=f2bf(v[j]);
        qh[dc][j]=(short)h;
        ql[dc][j]=(short)f2bf(v[j]-bf2f(h));
      }
    }
  }
  if(t<32) M_l[t]=Mb[hb+s0+t];
  f32x4 accO[11];
#pragma unroll
  for(int n=0;n<11;n++) accO[n]={0.f,0.f,0.f,0.f};
  __syncthreads();

  const float scale=0.05455447256f;           // 336^-0.5
  int it=0;
  for(int c=seg;c<nch;c+=TS_,it++){
    const int t0=c<<5;
    // ---- QK: B-frags direct from global (L2-resident, pipelined) ----
    const size_t kb0=(((size_t)head*128+(size_t)(c*2+tt))*11)*512+(size_t)l*8;
    f32x4 aq0={0,0,0,0}, aq1={0,0,0,0}, aq2={0,0,0,0};
#pragma unroll
    for(int dc=0;dc<11;dc++){
      const bf16x8 kh=*reinterpret_cast<const bf16x8*>(&khi[kb0+(size_t)dc*512]);
      const bf16x8 kl=*reinterpret_cast<const bf16x8*>(&klo[kb0+(size_t)dc*512]);
      aq0=__builtin_amdgcn_mfma_f32_16x16x32_bf16(qh[dc],kh,aq0,0,0,0);
      aq1=__builtin_amdgcn_mfma_f32_16x16x32_bf16(ql[dc],kh,aq1,0,0,0);
      aq2=__builtin_amdgcn_mfma_f32_16x16x32_bf16(qh[dc],kl,aq2,0,0,0);
    }
    // ---- mask/exp -> Sc bf16 (dbuf) ----
    const float al=ab[hb+t0+tt*16+lm];
    const int tg=t0+tt*16+lm, buf=it&1;
#pragma unroll
    for(int r=0;r<4;r++){
      const int srow=st*16+quad*4+r;
      const float qk=aq0[r]+aq1[r]+aq2[r];
      const float e=fminf(al-M_l[srow],0.f);
      const float msk=(tg<=s0+srow)?1.f:0.f;
      Sc[buf][srow][tt*16+lm]=(short)f2bf(msk*(qk*scale*expf(e)));
    }
    __syncthreads();                          // only barrier per chunk
    // ---- PV: A-frag from LDS, B-frags direct from global ----
    const bf16x8 scf=*reinterpret_cast<const bf16x8*>(&Sc[buf][st*16+lm][quad*8]);
    const size_t vb0=(((size_t)head*64+c)*22+(size_t)(tt*11))*512+(size_t)l*8;
#pragma unroll
    for(int nt=0;nt<11;nt++){
      const bf16x8 vf=*reinterpret_cast<const bf16x8*>(&vTf[vb0+(size_t)nt*512]);
      accO[nt]=__builtin_amdgcn_mfma_f32_16x16x32_bf16(scf,vf,accO[nt],0,0,0);
    }
  }

  // ---- atomic-accumulate partials ----
  const size_t pbase=((size_t)(head*64+sblk))*32;
#pragma unroll
  for(int nt=0;nt<11;nt++){
    const int col=tt*176+nt*16+lm;
#pragma unroll
    for(int r=0;r<4;r++){
      const int srow=st*16+quad*4+r;
      const float val=accO[nt][r];
      if(col<336){ if(val!=0.f) atomicAdd(&part[(pbase+srow)*336+col],val); }
      else if(col==336){ if(val!=0.f) atomicAdd(&rsum[pbase+srow],val); }
    }
  }
}

// ============================================================================
// finalize: n-normalizer + per-head groupnorm + hout write. Block per (sblk,head).
// ============================================================================
__global__ __launch_bounds__(256) void finalize_k(const float* __restrict__ part,
                                                  const float* __restrict__ rsum,
                                                  const float* __restrict__ mtb,
                                                  const float* __restrict__ lnw,
                                                  float* __restrict__ hout){
  const int sblk=blockIdx.x, head=blockIdx.y;
  const int bI=head>>2, nh=head&3;
  const int s0=sblk*32;
  const int t=threadIdx.x, row=t>>3, sub=t&7;
  __shared__ float red1[32][8], red2[32][8];
  __shared__ float mu_s[32], rs_s[32], inv_s[32];
  const size_t pbase=((size_t)(head*64+sblk))*32;
  const float* prow=part+(pbase+row)*336;
  float s1=0.f,s2=0.f;
  for(int c=sub;c<336;c+=8){ const float v=prow[c]; s1+=v; s2+=v*v; }
  red1[row][sub]=s1; red2[row][sub]=s2;
  __syncthreads();
  if(sub==0){
    float a1=0.f,a2=0.f;
#pragma unroll
    for(int j=0;j<8;j++){ a1+=red1[row][j]; a2+=red2[row][j]; }
    const float mt=mtb[(size_t)head*S_+s0+row];
    const float nn=fmaxf(fabsf(rsum[pbase+row]), expf(fminf(fmaxf(-mt,-60.f),60.f)));
    const float inv=1.f/(nn+1e-6f);
    const float mu=a1*inv/336.f;
    const float var=a2*inv*inv/336.f-mu*mu;
    inv_s[row]=inv; mu_s[row]=mu;
    rs_s[row]=rsqrtf(fmaxf(var,0.f)+1e-5f);
  }
  __syncthreads();
  const float inv=inv_s[row], mu=mu_s[row], rs=rs_s[row];
  float* orow=hout+((size_t)(bI*S_+s0+row))*H_+nh*DH_;
  for(int c=sub;c<336;c+=8)
    orow[c]=(prow[c]*inv-mu)*rs*lnw[nh*DH_+c];
}

// ---- h_state = (h_out + skip*act) * silu(z) ----
__global__ __launch_bounds__(256) void hstate_k(const float* __restrict__ hout,
                                                const float* __restrict__ act,
                                                const float* __restrict__ xin,
                                                const float* __restrict__ skip,
                                                float* __restrict__ hs){
  const int i=blockIdx.x*256+threadIdx.x;
  if(i>=(int)N_BSH) return;
  const int bs=i/H_, h=i-bs*H_;
  const float z=xin[(size_t)bs*H2_+H_+h];
  hs[(size_t)bs*H_+h]=(hout[(size_t)bs*H_+h]+skip[h]*act[(size_t)bs*H_+h])*siluf(z);
}

// ============================================================================
extern "C" void kernel_launch(void* const* d_in, const int* in_sizes, int n_in,
                              void* d_out, int out_size, void* d_ws, size_t ws_size,
                              hipStream_t stream){
  float* ws=(float*)d_ws;
  int* flag=(int*)ws;

  float* igb  = ws+O_IGB;
  float* logfb= ws+O_LOGF;
  float* ab   = ws+O_AB;
  float* Mbuf = ws+O_MB;
  float* mtb  = ws+O_MTB;
  float* f_ck = ws+O_CK;
  float* f_cb = ws+O_CB;
  float* f_wq = ws+O_WQ;
  float* f_wk = ws+O_WK;
  float* f_wv = ws+O_WV;
  float* f_wig= ws+O_WIG;
  float* f_big= ws+O_BIG;
  float* f_wfg= ws+O_WFG;
  float* f_bfg= ws+O_BFG;
  float* f_lnw= ws+O_LNW;
  float* f_skp= ws+O_SKP;
  float* f_x  = ws+O_FX;
  float* f_wup= ws+O_FWUP;
  float* f_wdn= ws+O_FWDN;
  float* xin  = ws+O_XIN;
  float* act  = ws+O_ACT;
  float* qb   = ws+O_QB;
  float* kb   = ws+O_KB;
  float* vb   = ws+O_VB;
  float* hout = ws+O_HOUT;
  float* hs   = qb;                            // alias: q dead after mlstm_k
  float* outf = f_x;                           // alias: khi dead after mlstm_k
  unsigned short* khi=(unsigned short*)f_x;    // f_x+f_wup dead after up-gemm
  unsigned short* klo=khi+KSPLIT_SHORTS;
  unsigned short* vTf=(unsigned short*)kb;     // kb dead after gates+kprep
  float* partb=vb;                             // vb dead after vprep; 8*64*32*336==N_BSH
  float* rsumb=igb;                            // igb dead after scan_k

  detect_k<<<1,256,0,stream>>>((const unsigned short*)d_in[0],flag);
  auto cvt=[&](int idx,float* dst,size_t n){
    convert_k<<<(int)((n+255)/256),256,0,stream>>>(d_in[idx],dst,(int)n,flag);
  };
  cvt(0,f_x,N_X);   cvt(1,f_wup,N_WUP); cvt(2,f_ck,N_CK);  cvt(3,f_cb,H_);
  cvt(4,f_wq,N_WH); cvt(5,f_wk,N_WH);   cvt(6,f_wv,N_WH);  cvt(7,f_wig,N_WG);
  cvt(8,f_big,4);   cvt(9,f_wfg,N_WG);  cvt(10,f_bfg,4);   cvt(11,f_lnw,H_);
  cvt(12,f_skp,H_); cvt(13,f_wdn,N_WDN);

  gemm_k<<<dim3(H2_/64,BS_/64),256,0,stream>>>(f_x,f_wup,xin,BS_,H2_,E_,E_,H2_,H2_);
  conv_act_k<<<(int)((N_BSH+255)/256),256,0,stream>>>(xin,f_ck,f_cb,act);
  qkv_k<<<(int)((N_BSH+255)/256),256,0,stream>>>(act,xin,f_wq,f_wk,f_wv,qb,kb,vb);
  gates_k<<<(BS_*NH_+255)/256,256,0,stream>>>(qb,kb,vb,f_wig,f_big,f_wfg,f_bfg,igb,logfb);
  kprep_k<<<8*128,256,0,stream>>>(kb,khi,klo);
  vprep_k<<<8*64,256,0,stream>>>(vb,vTf);
  scan_k<<<B_*NH_,256,0,stream>>>(igb,logfb,ab,Mbuf,mtb);
  hipMemsetAsync(partb,0,N_BSH*sizeof(float),stream);     // after vprep/scan
  hipMemsetAsync(rsumb,0,(size_t)NG_*sizeof(float),stream);
  mlstm_k<<<dim3(S_/32,B_*NH_,TS_),256,0,stream>>>(qb,khi,klo,vTf,ab,Mbuf,partb,rsumb);
  finalize_k<<<dim3(S_/32,B_*NH_),256,0,stream>>>(partb,rsumb,mtb,f_lnw,hout);
  hstate_k<<<(int)((N_BSH+255)/256),256,0,stream>>>(hout,act,xin,f_skp,hs);
  gemm_k<<<dim3(E_/64,BS_/64),256,0,stream>>>(hs,f_wdn,outf,BS_,E_,H_,H_,E_,E_);
  out_cast_k<<<(int)((N_X+255)/256),256,0,stream>>>(outf,d_out,flag);
}

// Round 9
// 1187.004 us; speedup vs baseline: 1.4535x; 1.2815x over previous
//
#include <hip/hip_runtime.h>
#include <cmath>

#define DI __device__ __forceinline__

constexpr int B_=2, S_=2048, E_=1024, H_=1344, NH_=4, DH_=336;
constexpr int BS_=B_*S_, H2_=2*H_;
constexpr int NG_=B_*NH_*S_;   // 16384
constexpr int TS_=4;           // split-K t-segments

constexpr size_t N_X=(size_t)BS_*E_;
constexpr size_t N_WUP=(size_t)E_*H2_;
constexpr size_t N_WDN=(size_t)H_*E_;
constexpr size_t N_BSH=(size_t)BS_*H_;
constexpr size_t N_BSH2=(size_t)BS_*H2_;
constexpr size_t N_WH=5376, N_WG=16128, N_CK=4*H_;

// ---- ws layout (floats); identical to rounds 4-8 (passing) ----
constexpr size_t O_IGB = 64;
constexpr size_t O_LOGF= O_IGB + NG_;
constexpr size_t O_AB  = O_LOGF+ NG_;
constexpr size_t O_MB  = O_AB  + NG_;
constexpr size_t O_MTB = O_MB  + NG_;
constexpr size_t O_CK  = O_MTB + NG_;
constexpr size_t O_CB  = O_CK  + N_CK;
constexpr size_t O_WQ  = O_CB  + H_;
constexpr size_t O_WK  = O_WQ  + N_WH;
constexpr size_t O_WV  = O_WK  + N_WH;
constexpr size_t O_WIG = O_WV  + N_WH;
constexpr size_t O_BIG = O_WIG + N_WG;
constexpr size_t O_WFG = O_BIG + 16;
constexpr size_t O_BFG = O_WFG + N_WG;
constexpr size_t O_LNW = O_BFG + 16;
constexpr size_t O_SKP = O_LNW + H_;
constexpr size_t O_FX  = O_SKP + H_;
constexpr size_t O_FWUP= O_FX  + N_X;
constexpr size_t O_FWDN= O_FWUP+ N_WUP;
constexpr size_t O_XIN = O_FWDN+ N_WDN;
constexpr size_t O_ACT = O_XIN + N_BSH2;
constexpr size_t O_QB  = O_ACT + N_BSH;
constexpr size_t O_KB  = O_QB  + N_BSH;
constexpr size_t O_VB  = O_KB  + N_BSH;
constexpr size_t O_HOUT= O_VB  + N_BSH;

// khi/klo: [head][tile=t/16][dc=0..10][l][8] bf16 (B-frag 16x16x32)
constexpr size_t KSPLIT_SHORTS=(size_t)8*128*11*64*8;  // 5,767,168
// vTf: [head][tc=t/32][ntg=0..21][l][8] bf16; n==336 -> 1.0 (rowsum), n>336 -> 0
constexpr size_t VT_SHORTS=(size_t)8*64*22*64*8;       // 5,767,168
// part: linear row = head*2048 + s, 336 cols fp32 (aliases vb == N_BSH floats)
// rsum: linear head*2048 + s (aliases igb == NG_ floats)

typedef __attribute__((ext_vector_type(8))) short bf16x8;
typedef __attribute__((ext_vector_type(4))) float f32x4;

DI float bf2f(unsigned int u){union{unsigned int i;float f;}v;v.i=(u&0xffffu)<<16;return v.f;}
DI unsigned short f2bf(float f){union{float f;unsigned int i;}v;v.f=f;unsigned int x=v.i;
  return (unsigned short)((x+0x7fffu+((x>>16)&1u))>>16);}
DI float siluf(float x){return x/(1.f+expf(-x));}
DI float logsigf(float x){return (x>=0.f)?-log1pf(expf(-x)):x-log1pf(expf(x));}
DI void load4(const float* p, float* d){float4 v=*reinterpret_cast<const float4*>(p);
  d[0]=v.x;d[1]=v.y;d[2]=v.z;d[3]=v.w;}

// ---- dtype detect (fp32 proven in round 4; keep the guard) ----
__global__ __launch_bounds__(256) void detect_k(const unsigned short* __restrict__ xraw,
                                                int* __restrict__ flag){
  __shared__ int cnt_s;
  if(threadIdx.x==0) cnt_s=0;
  __syncthreads();
  int c=0;
  for(int i=threadIdx.x;i<2048;i+=256){
    const unsigned e=(xraw[i]>>7)&0xFFu;
    if(e>=0x90u) c++;
  }
  atomicAdd(&cnt_s,c);
  __syncthreads();
  if(threadIdx.x==0) *flag=(cnt_s>16)?0:1;
}

__global__ __launch_bounds__(256) void convert_k(const void* __restrict__ src,
                                                 float* __restrict__ dst,int n,
                                                 const int* __restrict__ flag){
  const int i=blockIdx.x*256+threadIdx.x;
  if(i>=n) return;
  if(*flag) dst[i]=bf2f(((const unsigned short*)src)[i]);
  else      dst[i]=((const float*)src)[i];
}

__global__ __launch_bounds__(256) void out_cast_k(const float* __restrict__ src,void* dst,
                                                  const int* __restrict__ flag){
  const int i=blockIdx.x*256+threadIdx.x;
  if(i>=(int)N_X) return;
  const float v=src[i];
  if(*flag) ((unsigned short*)dst)[i]=f2bf(v);
  else      ((float*)dst)[i]=v;
}

// ============================================================================
// 64x64x16 tiled fp32 GEMM, 4x4 register blocking (rounds 5-8, passing).
// ============================================================================
__global__ __launch_bounds__(256) void gemm_k(const float* __restrict__ A,
                                              const float* __restrict__ B,
                                              float* __restrict__ C,
                                              int M,int N,int Kd,int lda,int ldb,int ldc){
  __shared__ float As[16][68];
  __shared__ float Bs[16][68];
  const int t=threadIdx.x;
  const int bn=blockIdx.x*64, bm=blockIdx.y*64;
  const int tx=t&15, ty=t>>4;
  const int a_row=t>>2, a_k4=(t&3)*4;
  const int b_kk=t>>4, b_n4=(t&15)*4;
  float acc[4][4]={};
  for(int k0=0;k0<Kd;k0+=16){
    float av[4], bv[4];
    load4(&A[(size_t)(bm+a_row)*lda+k0+a_k4], av);
    load4(&B[(size_t)(k0+b_kk)*ldb+bn+b_n4], bv);
    __syncthreads();
#pragma unroll
    for(int i=0;i<4;i++) As[a_k4+i][a_row]=av[i];
    *reinterpret_cast<float4*>(&Bs[b_kk][b_n4])=make_float4(bv[0],bv[1],bv[2],bv[3]);
    __syncthreads();
#pragma unroll
    for(int kk=0;kk<16;kk++){
      float a4[4], b4[4];
      load4(&As[kk][ty*4], a4);
      load4(&Bs[kk][tx*4], b4);
#pragma unroll
      for(int i=0;i<4;i++)
#pragma unroll
        for(int j=0;j<4;j++) acc[i][j]+=a4[i]*b4[j];
    }
  }
#pragma unroll
  for(int i=0;i<4;i++)
#pragma unroll
    for(int j=0;j<4;j++)
      C[(size_t)(bm+ty*4+i)*ldc+bn+tx*4+j]=acc[i][j];
}

// ---- causal depthwise conv(K=4)+bias -> SiLU ----
__global__ __launch_bounds__(256) void conv_act_k(const float* __restrict__ xin,
                                                  const float* __restrict__ ck,
                                                  const float* __restrict__ cb,
                                                  float* __restrict__ act){
  const int i=blockIdx.x*256+threadIdx.x;
  if(i>=(int)N_BSH) return;
  const int bs=i/H_, h=i-bs*H_;
  const int b=bs/S_, s=bs-b*S_;
  float xc=cb[h];
#pragma unroll
  for(int w=0;w<4;w++){
    const int sr=s-3+w;
    if(sr>=0) xc+=xin[(size_t)(b*S_+sr)*H2_+h]*ck[w*H_+h];
  }
  act[(size_t)bs*H_+h]=siluf(xc);
}

// ---- headwise q/k/v ----
__global__ __launch_bounds__(256) void qkv_k(const float* __restrict__ act,
                                             const float* __restrict__ xin,
                                             const float* __restrict__ Wq,
                                             const float* __restrict__ Wk,
                                             const float* __restrict__ Wv,
                                             float* __restrict__ qb,float* __restrict__ kb,
                                             float* __restrict__ vb){
  const int i=blockIdx.x*256+threadIdx.x;
  if(i>=(int)N_BSH) return;
  const int bs=i/H_, h=i-bs*H_;
  const int b=bs/S_, s=bs-b*S_;
  const int ph=h>>2, o=h&3, base=ph*4;
  float q=0.f,k=0.f,v=0.f;
#pragma unroll
  for(int d=0;d<4;d++){
    const float a=act[(size_t)bs*H_+base+d];
    const float x=xin[(size_t)bs*H2_+base+d];
    q+=a*Wq[ph*16+d*4+o];
    k+=a*Wk[ph*16+d*4+o];
    v+=x*Wv[ph*16+d*4+o];
  }
  const int nh=h/DH_, dh=h-nh*DH_;
  const size_t off=((size_t)(b*NH_+nh)*S_+s)*DH_+dh;
  qb[off]=q; kb[off]=k; vb[off]=v;
}

// ---- gate pre-activations (round-4, passing) ----
__global__ __launch_bounds__(256) void gates_k(const float* __restrict__ qb,
                                               const float* __restrict__ kb,
                                               const float* __restrict__ vb,
                                               const float* __restrict__ Wig,
                                               const float* __restrict__ big,
                                               const float* __restrict__ Wfg,
                                               const float* __restrict__ bfg,
                                               float* __restrict__ igb,float* __restrict__ logfb){
  const int i=blockIdx.x*256+threadIdx.x;
  if(i>=BS_*NH_) return;
  const int bs=i>>2, n=i&3;
  const int b=bs/S_, s=bs-b*S_;
  float sig=0.f,sfg=0.f;
  for(int nh=0;nh<NH_;nh++){
    const size_t rb=((size_t)(b*NH_+nh)*S_+s)*DH_;
    for(int dh=0;dh<DH_;dh++){
      const int h=nh*DH_+dh;
      const float q=qb[rb+dh], k=kb[rb+dh], v=vb[rb+dh];
      sig+=q*Wig[h*4+n]+k*Wig[(H_+h)*4+n]+v*Wig[(2*H_+h)*4+n];
      sfg+=q*Wfg[h*4+n]+k*Wfg[(H_+h)*4+n]+v*Wfg[(2*H_+h)*4+n];
    }
  }
  const size_t off=(size_t)(b*NH_+n)*S_+s;
  igb[off]=sig+big[n];
  logfb[off]=logsigf(sfg+bfg[n]);
}

// ---- K prep: split fp32 K into hi/lo bf16, MFMA B-fragment tile layout ----
__global__ __launch_bounds__(256) void kprep_k(const float* __restrict__ kb,
                                               unsigned short* __restrict__ khi,
                                               unsigned short* __restrict__ klo){
  const int blk=blockIdx.x;                 // 8 heads * 128 t-tiles
  const int head=blk>>7, tt=blk&127;
  const size_t obase=(size_t)blk*11*512;
  for(int slot=threadIdx.x; slot<704; slot+=256){
    const int dc=slot>>6, ll=slot&63, quad=ll>>4, lm=ll&15;
    const int tg=tt*16+lm, dbase=dc*32+quad*8;
    float v[8];
    if(dbase<336){
      load4(&kb[((size_t)head*S_+tg)*DH_+dbase],v);
      load4(&kb[((size_t)head*S_+tg)*DH_+dbase+4],v+4);
    } else { for(int j=0;j<8;j++) v[j]=0.f; }
    unsigned short hi8[8], lo8[8];
#pragma unroll
    for(int j=0;j<8;j++){
      hi8[j]=f2bf(v[j]);
      lo8[j]=f2bf(v[j]-bf2f(hi8[j]));
    }
    const size_t o=obase+(size_t)(dc*64+ll)*8;
    uint4 ph, pl;
    ph.x=(unsigned)hi8[0]|((unsigned)hi8[1]<<16); ph.y=(unsigned)hi8[2]|((unsigned)hi8[3]<<16);
    ph.z=(unsigned)hi8[4]|((unsigned)hi8[5]<<16); ph.w=(unsigned)hi8[6]|((unsigned)hi8[7]<<16);
    pl.x=(unsigned)lo8[0]|((unsigned)lo8[1]<<16); pl.y=(unsigned)lo8[2]|((unsigned)lo8[3]<<16);
    pl.z=(unsigned)lo8[4]|((unsigned)lo8[5]<<16); pl.w=(unsigned)lo8[6]|((unsigned)lo8[7]<<16);
    *reinterpret_cast<uint4*>(&khi[o])=ph;
    *reinterpret_cast<uint4*>(&klo[o])=pl;
  }
}

// ---- V prep: V^T bf16 in MFMA B-fragment tile layout; col 336 = ones ----
__global__ __launch_bounds__(256) void vprep_k(const float* __restrict__ vb,
                                               unsigned short* __restrict__ vTf){
  const int blk=blockIdx.x;                 // 8 heads * 64 t-chunks
  const int head=blk>>6, tc=blk&63;
  const size_t obase=(size_t)blk*22*512;
  for(int slot=threadIdx.x; slot<1408; slot+=256){
    const int ntg=slot>>6, ll=slot&63, quad=ll>>4, lm=ll&15;
    const int n=ntg*16+lm, t0=tc*32+quad*8;
    unsigned short h8[8];
#pragma unroll
    for(int j=0;j<8;j++){
      float val;
      if(n<336)       val=vb[((size_t)head*S_+t0+j)*DH_+n];
      else if(n==336) val=1.f;
      else            val=0.f;
      h8[j]=f2bf(val);
    }
    uint4 pk;
    pk.x=(unsigned)h8[0]|((unsigned)h8[1]<<16); pk.y=(unsigned)h8[2]|((unsigned)h8[3]<<16);
    pk.z=(unsigned)h8[4]|((unsigned)h8[5]<<16); pk.w=(unsigned)h8[6]|((unsigned)h8[7]<<16);
    *reinterpret_cast<uint4*>(&vTf[obase+(size_t)(ntg*64+ll)*8])=pk;
  }
}

// ---- parallel per-head scan (rounds 7-8, passing) ----
__global__ __launch_bounds__(256) void scan_k(const float* __restrict__ igb,
                                              const float* __restrict__ logfb,
                                              float* __restrict__ ab,float* __restrict__ Mb,
                                              float* __restrict__ mtb){
  const int head=blockIdx.x, t=threadIdx.x;
  __shared__ float sh[256];
  const float* lf=logfb+(size_t)head*S_;
  const float* ig=igb+(size_t)head*S_;
  float lc[8];
  float run=0.f;
#pragma unroll
  for(int i=0;i<8;i++){ run+=lf[t*8+i]; lc[i]=run; }
  sh[t]=run;
  for(int st=1;st<256;st<<=1){
    __syncthreads();
    const float v=(t>=st)?sh[t-st]:0.f;
    __syncthreads();
    sh[t]+=v;
  }
  __syncthreads();
  const float off=(t==0)?0.f:sh[t-1];
  __syncthreads();
  float av[8],mv[8],cv[8];
  float mrun=-1e30f;
#pragma unroll
  for(int i=0;i<8;i++){
    cv[i]=off+lc[i];
    av[i]=ig[t*8+i]-cv[i];
    mrun=fmaxf(mrun,av[i]);
    mv[i]=mrun;
  }
  sh[t]=mrun;
  for(int st=1;st<256;st<<=1){
    __syncthreads();
    const float v=(t>=st)?sh[t-st]:-1e30f;
    __syncthreads();
    sh[t]=fmaxf(sh[t],v);
  }
  __syncthreads();
  const float moff=(t==0)?-1e30f:sh[t-1];
#pragma unroll
  for(int i=0;i<8;i++){
    const float Mi=fmaxf(moff,mv[i]);
    const size_t j=(size_t)head*S_+t*8+i;
    ab[j]=av[i]; Mb[j]=Mi; mtb[j]=cv[i]+Mi;
  }
}

// ============================================================================
// mLSTM v6 — 64-row supertiles, barrier-free K-loop, XCD-pinned heads.
// 1-D grid 1024: head=bid&7 (XCD pin), seg=(bid>>3)&3, sb=31-(bid>>5).
// 4 waves x 16 rows; each wave owns all 352 n-cols (accO[22]).
// Per chunk (32 t): QK 2 t-tiles x 3 split MFMA chains (frag-direct loads),
// Sc transpose via PER-WAVE LDS (no __syncthreads), PV 22 MFMAs.
// Partials atomically added to part/rsum (finalize_k normalizes).
// ============================================================================
__global__ __launch_bounds__(256) void mlstm_k(
    const float* __restrict__ qb, const unsigned short* __restrict__ khi,
    const unsigned short* __restrict__ klo, const unsigned short* __restrict__ vTf,
    const float* __restrict__ ab, const float* __restrict__ Mb,
    float* __restrict__ part, float* __restrict__ rsum){
  const int bid=blockIdx.x;
  const int head=bid&7;                       // XCD-pin heuristic
  const int r2=bid>>3;
  const int seg=r2&3;
  const int sb=31-(r2>>2);                    // heavy supertiles first
  const int s0=sb*64;
  const int nch=2*sb+2;
  if(seg>=nch) return;
  const int t=threadIdx.x, w=t>>6, l=t&63, lm=l&15, quad=l>>4;
  const int ws0=s0+w*16;

  __shared__ short Sc[4][16][40];             // per-wave buffers; no barriers

  const size_t hb=(size_t)head*S_;
  // ---- persistent Q fragments (split hi/lo bf16), 11 d-chunks ----
  bf16x8 qh[11], ql[11];
  {
    const float* qrow=qb+(hb+ws0+lm)*DH_;
#pragma unroll
    for(int dc=0;dc<11;dc++){
      const int dbase=dc*32+quad*8;
      float v[8];
      if(dbase<336){ load4(qrow+dbase,v); load4(qrow+dbase+4,v+4); }
      else { for(int j=0;j<8;j++) v[j]=0.f; }
#pragma unroll
      for(int j=0;j<8;j++){
        const unsigned short h=f2bf(v[j]);
        qh[dc][j]=(short)h;
        ql[dc][j]=(short)f2bf(v[j]-bf2f(h));
      }
    }
  }
  float Mr[4];
#pragma unroll
  for(int r=0;r<4;r++) Mr[r]=Mb[hb+ws0+quad*4+r];

  f32x4 accO[22];
#pragma unroll
  for(int n=0;n<22;n++) accO[n]={0.f,0.f,0.f,0.f};

  const float scale=0.05455447256f;           // 336^-0.5

  for(int c=seg;c<nch;c+=TS_){
    const int t0=c<<5;
    const float al0=ab[hb+t0+lm];
    const float al1=ab[hb+t0+16+lm];
    // ---- QK: two t-tiles, frag-direct K loads ----
#pragma unroll
    for(int tt=0;tt<2;tt++){
      const size_t kb0=(((size_t)head*128+(size_t)(c*2+tt))*11)*512+(size_t)l*8;
      f32x4 a0={0,0,0,0}, a1={0,0,0,0}, a2={0,0,0,0};
#pragma unroll
      for(int dc=0;dc<11;dc++){
        const bf16x8 kh=*reinterpret_cast<const bf16x8*>(&khi[kb0+(size_t)dc*512]);
        const bf16x8 kl=*reinterpret_cast<const bf16x8*>(&klo[kb0+(size_t)dc*512]);
        a0=__builtin_amdgcn_mfma_f32_16x16x32_bf16(qh[dc],kh,a0,0,0,0);
        a1=__builtin_amdgcn_mfma_f32_16x16x32_bf16(ql[dc],kh,a1,0,0,0);
        a2=__builtin_amdgcn_mfma_f32_16x16x32_bf16(qh[dc],kl,a2,0,0,0);
      }
      const float al=(tt==0)?al0:al1;
      const int tg=t0+tt*16+lm;
#pragma unroll
      for(int r=0;r<4;r++){
        const int srow=quad*4+r;
        const float qk=a0[r]+a1[r]+a2[r];
        const float e=fminf(al-Mr[r],0.f);
        const float msk=(tg<=ws0+srow)?1.f:0.f;
        Sc[w][srow][tt*16+lm]=(short)f2bf(msk*(qk*scale*expf(e)));
      }
    }
    // ---- PV: A-frag from own wave's Sc (in-wave LDS ordering), V frag-direct ----
    const bf16x8 scf=*reinterpret_cast<const bf16x8*>(&Sc[w][lm][quad*8]);
    const size_t vb0=(((size_t)head*64+c)*22)*512+(size_t)l*8;
#pragma unroll
    for(int nt=0;nt<22;nt++){
      const bf16x8 vf=*reinterpret_cast<const bf16x8*>(&vTf[vb0+(size_t)nt*512]);
      accO[nt]=__builtin_amdgcn_mfma_f32_16x16x32_bf16(scf,vf,accO[nt],0,0,0);
    }
  }

  // ---- atomic-accumulate partials (linear row = head*2048 + s) ----
  const size_t pbase=(size_t)head*2048+ws0;
#pragma unroll
  for(int nt=0;nt<22;nt++){
    const int col=nt*16+lm;
#pragma unroll
    for(int r=0;r<4;r++){
      const int srow=quad*4+r;
      const float val=accO[nt][r];
      if(col<336){ if(val!=0.f) atomicAdd(&part[(pbase+srow)*336+col],val); }
      else if(col==336){ if(val!=0.f) atomicAdd(&rsum[pbase+srow],val); }
    }
  }
}

// ============================================================================
// finalize: n-normalizer + per-head groupnorm + hout write. Block per (32 rows, head).
// ============================================================================
__global__ __launch_bounds__(256) void finalize_k(const float* __restrict__ part,
                                                  const float* __restrict__ rsum,
                                                  const float* __restrict__ mtb,
                                                  const float* __restrict__ lnw,
                                                  float* __restrict__ hout){
  const int sblk=blockIdx.x, head=blockIdx.y;
  const int bI=head>>2, nh=head&3;
  const int s0=sblk*32;
  const int t=threadIdx.x, row=t>>3, sub=t&7;
  __shared__ float red1[32][8], red2[32][8];
  __shared__ float mu_s[32], rs_s[32], inv_s[32];
  const size_t pbase=(size_t)head*2048+s0;
  const float* prow=part+(pbase+row)*336;
  float s1=0.f,s2=0.f;
  for(int c=sub;c<336;c+=8){ const float v=prow[c]; s1+=v; s2+=v*v; }
  red1[row][sub]=s1; red2[row][sub]=s2;
  __syncthreads();
  if(sub==0){
    float a1=0.f,a2=0.f;
#pragma unroll
    for(int j=0;j<8;j++){ a1+=red1[row][j]; a2+=red2[row][j]; }
    const float mt=mtb[(size_t)head*S_+s0+row];
    const float nn=fmaxf(fabsf(rsum[pbase+row]), expf(fminf(fmaxf(-mt,-60.f),60.f)));
    const float inv=1.f/(nn+1e-6f);
    const float mu=a1*inv/336.f;
    const float var=a2*inv*inv/336.f-mu*mu;
    inv_s[row]=inv; mu_s[row]=mu;
    rs_s[row]=rsqrtf(fmaxf(var,0.f)+1e-5f);
  }
  __syncthreads();
  const float inv=inv_s[row], mu=mu_s[row], rs=rs_s[row];
  float* orow=hout+((size_t)(bI*S_+s0+row))*H_+nh*DH_;
  for(int c=sub;c<336;c+=8)
    orow[c]=(prow[c]*inv-mu)*rs*lnw[nh*DH_+c];
}

// ---- h_state = (h_out + skip*act) * silu(z) ----
__global__ __launch_bounds__(256) void hstate_k(const float* __restrict__ hout,
                                                const float* __restrict__ act,
                                                const float* __restrict__ xin,
                                                const float* __restrict__ skip,
                                                float* __restrict__ hs){
  const int i=blockIdx.x*256+threadIdx.x;
  if(i>=(int)N_BSH) return;
  const int bs=i/H_, h=i-bs*H_;
  const float z=xin[(size_t)bs*H2_+H_+h];
  hs[(size_t)bs*H_+h]=(hout[(size_t)bs*H_+h]+skip[h]*act[(size_t)bs*H_+h])*siluf(z);
}

// ============================================================================
extern "C" void kernel_launch(void* const* d_in, const int* in_sizes, int n_in,
                              void* d_out, int out_size, void* d_ws, size_t ws_size,
                              hipStream_t stream){
  float* ws=(float*)d_ws;
  int* flag=(int*)ws;

  float* igb  = ws+O_IGB;
  float* logfb= ws+O_LOGF;
  float* ab   = ws+O_AB;
  float* Mbuf = ws+O_MB;
  float* mtb  = ws+O_MTB;
  float* f_ck = ws+O_CK;
  float* f_cb = ws+O_CB;
  float* f_wq = ws+O_WQ;
  float* f_wk = ws+O_WK;
  float* f_wv = ws+O_WV;
  float* f_wig= ws+O_WIG;
  float* f_big= ws+O_BIG;
  float* f_wfg= ws+O_WFG;
  float* f_bfg= ws+O_BFG;
  float* f_lnw= ws+O_LNW;
  float* f_skp= ws+O_SKP;
  float* f_x  = ws+O_FX;
  float* f_wup= ws+O_FWUP;
  float* f_wdn= ws+O_FWDN;
  float* xin  = ws+O_XIN;
  float* act  = ws+O_ACT;
  float* qb   = ws+O_QB;
  float* kb   = ws+O_KB;
  float* vb   = ws+O_VB;
  float* hout = ws+O_HOUT;
  float* hs   = qb;                            // alias: q dead after mlstm_k
  float* outf = f_x;                           // alias: khi dead after mlstm_k
  unsigned short* khi=(unsigned short*)f_x;    // f_x+f_wup dead after up-gemm
  unsigned short* klo=khi+KSPLIT_SHORTS;
  unsigned short* vTf=(unsigned short*)kb;     // kb dead after gates+kprep
  float* partb=vb;                             // vb dead after vprep
  float* rsumb=igb;                            // igb dead after scan_k

  detect_k<<<1,256,0,stream>>>((const unsigned short*)d_in[0],flag);
  auto cvt=[&](int idx,float* dst,size_t n){
    convert_k<<<(int)((n+255)/256),256,0,stream>>>(d_in[idx],dst,(int)n,flag);
  };
  cvt(0,f_x,N_X);   cvt(1,f_wup,N_WUP); cvt(2,f_ck,N_CK);  cvt(3,f_cb,H_);
  cvt(4,f_wq,N_WH); cvt(5,f_wk,N_WH);   cvt(6,f_wv,N_WH);  cvt(7,f_wig,N_WG);
  cvt(8,f_big,4);   cvt(9,f_wfg,N_WG);  cvt(10,f_bfg,4);   cvt(11,f_lnw,H_);
  cvt(12,f_skp,H_); cvt(13,f_wdn,N_WDN);

  gemm_k<<<dim3(H2_/64,BS_/64),256,0,stream>>>(f_x,f_wup,xin,BS_,H2_,E_,E_,H2_,H2_);
  conv_act_k<<<(int)((N_BSH+255)/256),256,0,stream>>>(xin,f_ck,f_cb,act);
  qkv_k<<<(int)((N_BSH+255)/256),256,0,stream>>>(act,xin,f_wq,f_wk,f_wv,qb,kb,vb);
  gates_k<<<(BS_*NH_+255)/256,256,0,stream>>>(qb,kb,vb,f_wig,f_big,f_wfg,f_bfg,igb,logfb);
  kprep_k<<<8*128,256,0,stream>>>(kb,khi,klo);
  vprep_k<<<8*64,256,0,stream>>>(vb,vTf);
  scan_k<<<B_*NH_,256,0,stream>>>(igb,logfb,ab,Mbuf,mtb);
  hipMemsetAsync(partb,0,N_BSH*sizeof(float),stream);
  hipMemsetAsync(rsumb,0,(size_t)NG_*sizeof(float),stream);
  mlstm_k<<<1024,256,0,stream>>>(qb,khi,klo,vTf,ab,Mbuf,partb,rsumb);
  finalize_k<<<dim3(S_/32,B_*NH_),256,0,stream>>>(partb,rsumb,mtb,f_lnw,hout);
  hstate_k<<<(int)((N_BSH+255)/256),256,0,stream>>>(hout,act,xin,f_skp,hs);
  gemm_k<<<dim3(E_/64,BS_/64),256,0,stream>>>(hs,f_wdn,outf,BS_,E_,H_,H_,E_,E_);
  out_cast_k<<<(int)((N_X+255)/256),256,0,stream>>>(outf,d_out,flag);
}

// Round 10
// 879.195 us; speedup vs baseline: 1.9624x; 1.3501x over previous
//
#include <hip/hip_runtime.h>
#include <cmath>

#define DI __device__ __forceinline__

constexpr int B_=2, S_=2048, E_=1024, H_=1344, NH_=4, DH_=336;
constexpr int BS_=B_*S_, H2_=2*H_;
constexpr int NG_=B_*NH_*S_;   // 16384
constexpr int TS_=4;           // split-K t-segments

constexpr size_t N_X=(size_t)BS_*E_;
constexpr size_t N_WUP=(size_t)E_*H2_;
constexpr size_t N_WDN=(size_t)H_*E_;
constexpr size_t N_BSH=(size_t)BS_*H_;
constexpr size_t N_BSH2=(size_t)BS_*H2_;
constexpr size_t N_WH=5376, N_WG=16128, N_CK=4*H_;

// ---- ws layout (floats); identical to rounds 4-9 (passing) ----
constexpr size_t O_IGB = 64;
constexpr size_t O_LOGF= O_IGB + NG_;
constexpr size_t O_AB  = O_LOGF+ NG_;
constexpr size_t O_MB  = O_AB  + NG_;
constexpr size_t O_MTB = O_MB  + NG_;
constexpr size_t O_CK  = O_MTB + NG_;
constexpr size_t O_CB  = O_CK  + N_CK;
constexpr size_t O_WQ  = O_CB  + H_;
constexpr size_t O_WK  = O_WQ  + N_WH;
constexpr size_t O_WV  = O_WK  + N_WH;
constexpr size_t O_WIG = O_WV  + N_WH;
constexpr size_t O_BIG = O_WIG + N_WG;
constexpr size_t O_WFG = O_BIG + 16;
constexpr size_t O_BFG = O_WFG + N_WG;
constexpr size_t O_LNW = O_BFG + 16;
constexpr size_t O_SKP = O_LNW + H_;
constexpr size_t O_FX  = O_SKP + H_;
constexpr size_t O_FWUP= O_FX  + N_X;
constexpr size_t O_FWDN= O_FWUP+ N_WUP;
constexpr size_t O_XIN = O_FWDN+ N_WDN;
constexpr size_t O_ACT = O_XIN + N_BSH2;
constexpr size_t O_QB  = O_ACT + N_BSH;
constexpr size_t O_KB  = O_QB  + N_BSH;
constexpr size_t O_VB  = O_KB  + N_BSH;
constexpr size_t O_HOUT= O_VB  + N_BSH;

// khi/klo: [head][tile=t/16][dc=0..10][l][8] bf16 (B-frag 16x16x32)
constexpr size_t KSPLIT_SHORTS=(size_t)8*128*11*64*8;  // 5,767,168
// vTf: [head][tc=t/32][ntg=0..21][l][8] bf16; n==336 -> 1.0 (rowsum), n>336 -> 0
constexpr size_t VT_SHORTS=(size_t)8*64*22*64*8;       // 5,767,168

typedef __attribute__((ext_vector_type(8))) short bf16x8;
typedef __attribute__((ext_vector_type(4))) float f32x4;

DI float bf2f(unsigned int u){union{unsigned int i;float f;}v;v.i=(u&0xffffu)<<16;return v.f;}
DI unsigned short f2bf(float f){union{float f;unsigned int i;}v;v.f=f;unsigned int x=v.i;
  return (unsigned short)((x+0x7fffu+((x>>16)&1u))>>16);}
DI float siluf(float x){return x/(1.f+expf(-x));}
DI float logsigf(float x){return (x>=0.f)?-log1pf(expf(-x)):x-log1pf(expf(x));}
DI void load4(const float* p, float* d){float4 v=*reinterpret_cast<const float4*>(p);
  d[0]=v.x;d[1]=v.y;d[2]=v.z;d[3]=v.w;}

// ---- dtype detect (fp32 proven in round 4; keep the guard) ----
__global__ __launch_bounds__(256) void detect_k(const unsigned short* __restrict__ xraw,
                                                int* __restrict__ flag){
  __shared__ int cnt_s;
  if(threadIdx.x==0) cnt_s=0;
  __syncthreads();
  int c=0;
  for(int i=threadIdx.x;i<2048;i+=256){
    const unsigned e=(xraw[i]>>7)&0xFFu;
    if(e>=0x90u) c++;
  }
  atomicAdd(&cnt_s,c);
  __syncthreads();
  if(threadIdx.x==0) *flag=(cnt_s>16)?0:1;
}

__global__ __launch_bounds__(256) void convert_k(const void* __restrict__ src,
                                                 float* __restrict__ dst,int n,
                                                 const int* __restrict__ flag){
  const int i=blockIdx.x*256+threadIdx.x;
  if(i>=n) return;
  if(*flag) dst[i]=bf2f(((const unsigned short*)src)[i]);
  else      dst[i]=((const float*)src)[i];
}

// ============================================================================
// A-fragment prep: out[((mt*kcn+kc)*64+l)*8+j] = A[mt*16+(l&15)][kc*32+(l>>4)*8+j]
// split into hi/lo bf16. flag==nullptr -> src is fp32.
// ============================================================================
__global__ __launch_bounds__(256) void aprep_k(const void* __restrict__ src,
                                               const int* __restrict__ flag,
                                               int kcn,int ldk,int total,
                                               unsigned short* __restrict__ hi,
                                               unsigned short* __restrict__ lo){
  const int slot=blockIdx.x*256+threadIdx.x;
  if(slot>=total) return;
  const int l=slot&63, rest=slot>>6;
  const int kc=rest%kcn, mt=rest/kcn;
  const int row=mt*16+(l&15), k0=kc*32+(l>>4)*8;
  const int fl=flag?*flag:0;
  float v[8];
  if(fl){
    const unsigned short* s=(const unsigned short*)src+(size_t)row*ldk+k0;
    const uint4 u=*reinterpret_cast<const uint4*>(s);
    v[0]=bf2f(u.x);v[1]=bf2f(u.x>>16);v[2]=bf2f(u.y);v[3]=bf2f(u.y>>16);
    v[4]=bf2f(u.z);v[5]=bf2f(u.z>>16);v[6]=bf2f(u.w);v[7]=bf2f(u.w>>16);
  }else{
    const float* s=(const float*)src+(size_t)row*ldk+k0;
    load4(s,v); load4(s+4,v+4);
  }
  unsigned short h8[8], l8[8];
#pragma unroll
  for(int j=0;j<8;j++){ h8[j]=f2bf(v[j]); l8[j]=f2bf(v[j]-bf2f(h8[j])); }
  uint4 ph,pl;
  ph.x=(unsigned)h8[0]|((unsigned)h8[1]<<16); ph.y=(unsigned)h8[2]|((unsigned)h8[3]<<16);
  ph.z=(unsigned)h8[4]|((unsigned)h8[5]<<16); ph.w=(unsigned)h8[6]|((unsigned)h8[7]<<16);
  pl.x=(unsigned)l8[0]|((unsigned)l8[1]<<16); pl.y=(unsigned)l8[2]|((unsigned)l8[3]<<16);
  pl.z=(unsigned)l8[4]|((unsigned)l8[5]<<16); pl.w=(unsigned)l8[6]|((unsigned)l8[7]<<16);
  *reinterpret_cast<uint4*>(&hi[(size_t)slot*8])=ph;
  *reinterpret_cast<uint4*>(&lo[(size_t)slot*8])=pl;
}

// ============================================================================
// B-fragment prep: out[((nt*kcn+kc)*64+l)*8+j] = B[kc*32+(l>>4)*8+j][nt*16+(l&15)]
// ============================================================================
__global__ __launch_bounds__(256) void bprep_k(const void* __restrict__ src,
                                               const int* __restrict__ flag,
                                               int kcn,int ldn,int total,
                                               unsigned short* __restrict__ hi,
                                               unsigned short* __restrict__ lo){
  const int slot=blockIdx.x*256+threadIdx.x;
  if(slot>=total) return;
  const int l=slot&63, rest=slot>>6;
  const int kc=rest%kcn, nt=rest/kcn;
  const int col=nt*16+(l&15), row0=kc*32+(l>>4)*8;
  const int fl=flag?*flag:0;
  float v[8];
  if(fl){
    const unsigned short* s=(const unsigned short*)src;
#pragma unroll
    for(int j=0;j<8;j++) v[j]=bf2f(s[(size_t)(row0+j)*ldn+col]);
  }else{
    const float* s=(const float*)src;
#pragma unroll
    for(int j=0;j<8;j++) v[j]=s[(size_t)(row0+j)*ldn+col];
  }
  unsigned short h8[8], l8[8];
#pragma unroll
  for(int j=0;j<8;j++){ h8[j]=f2bf(v[j]); l8[j]=f2bf(v[j]-bf2f(h8[j])); }
  uint4 ph,pl;
  ph.x=(unsigned)h8[0]|((unsigned)h8[1]<<16); ph.y=(unsigned)h8[2]|((unsigned)h8[3]<<16);
  ph.z=(unsigned)h8[4]|((unsigned)h8[5]<<16); ph.w=(unsigned)h8[6]|((unsigned)h8[7]<<16);
  pl.x=(unsigned)l8[0]|((unsigned)l8[1]<<16); pl.y=(unsigned)l8[2]|((unsigned)l8[3]<<16);
  pl.z=(unsigned)l8[4]|((unsigned)l8[5]<<16); pl.w=(unsigned)l8[6]|((unsigned)l8[7]<<16);
  *reinterpret_cast<uint4*>(&hi[(size_t)slot*8])=ph;
  *reinterpret_cast<uint4*>(&lo[(size_t)slot*8])=pl;
}

// ============================================================================
// MFMA GEMM: 128x64 tile, 4 waves x 2 row-tiles x 4 n-tiles, split-bf16
// 3-chain (AhBh+AlBh+AhBl), fp32 acc. No LDS, no barriers, frag-direct loads.
// C: fp32 (flag==nullptr) or flag-branched fp32/bf16 output.
// ============================================================================
__global__ __launch_bounds__(256) void gemm_mfma_k(
    const unsigned short* __restrict__ Ahi, const unsigned short* __restrict__ Alo,
    const unsigned short* __restrict__ Bhi, const unsigned short* __restrict__ Blo,
    void* __restrict__ C, const int* __restrict__ flag, int kcn, int ldc){
  const int t=threadIdx.x, w=t>>6, l=t&63, lm=l&15, quad=l>>4;
  const int bn=blockIdx.x*64, bm=blockIdx.y*128;
  const int mt0=(bm>>4)+w, mt1=mt0+4;
  const size_t a0=((size_t)mt0*kcn)*512+(size_t)l*8;
  const size_t a1=((size_t)mt1*kcn)*512+(size_t)l*8;
  const size_t b0=((size_t)(bn>>4)*kcn)*512+(size_t)l*8;
  f32x4 acc[2][4];
#pragma unroll
  for(int g=0;g<2;g++)
#pragma unroll
    for(int nt=0;nt<4;nt++) acc[g][nt]={0.f,0.f,0.f,0.f};
  for(int kc=0;kc<kcn;kc++){
    const bf16x8 ah0=*reinterpret_cast<const bf16x8*>(&Ahi[a0+(size_t)kc*512]);
    const bf16x8 al0=*reinterpret_cast<const bf16x8*>(&Alo[a0+(size_t)kc*512]);
    const bf16x8 ah1=*reinterpret_cast<const bf16x8*>(&Ahi[a1+(size_t)kc*512]);
    const bf16x8 al1=*reinterpret_cast<const bf16x8*>(&Alo[a1+(size_t)kc*512]);
#pragma unroll
    for(int nt=0;nt<4;nt++){
      const size_t bo=b0+((size_t)nt*kcn+kc)*512;
      const bf16x8 bh=*reinterpret_cast<const bf16x8*>(&Bhi[bo]);
      const bf16x8 bl=*reinterpret_cast<const bf16x8*>(&Blo[bo]);
      acc[0][nt]=__builtin_amdgcn_mfma_f32_16x16x32_bf16(ah0,bh,acc[0][nt],0,0,0);
      acc[0][nt]=__builtin_amdgcn_mfma_f32_16x16x32_bf16(al0,bh,acc[0][nt],0,0,0);
      acc[0][nt]=__builtin_amdgcn_mfma_f32_16x16x32_bf16(ah0,bl,acc[0][nt],0,0,0);
      acc[1][nt]=__builtin_amdgcn_mfma_f32_16x16x32_bf16(ah1,bh,acc[1][nt],0,0,0);
      acc[1][nt]=__builtin_amdgcn_mfma_f32_16x16x32_bf16(al1,bh,acc[1][nt],0,0,0);
      acc[1][nt]=__builtin_amdgcn_mfma_f32_16x16x32_bf16(ah1,bl,acc[1][nt],0,0,0);
    }
  }
  const int bf=flag?*flag:0;
#pragma unroll
  for(int g=0;g<2;g++)
#pragma unroll
    for(int nt=0;nt<4;nt++)
#pragma unroll
      for(int r=0;r<4;r++){
        const size_t idx=(size_t)(bm+g*64+w*16+quad*4+r)*ldc+bn+nt*16+lm;
        if(bf) ((unsigned short*)C)[idx]=f2bf(acc[g][nt][r]);
        else   ((float*)C)[idx]=acc[g][nt][r];
      }
}

// ---- causal depthwise conv(K=4)+bias -> SiLU ----
__global__ __launch_bounds__(256) void conv_act_k(const float* __restrict__ xin,
                                                  const float* __restrict__ ck,
                                                  const float* __restrict__ cb,
                                                  float* __restrict__ act){
  const int i=blockIdx.x*256+threadIdx.x;
  if(i>=(int)N_BSH) return;
  const int bs=i/H_, h=i-bs*H_;
  const int b=bs/S_, s=bs-b*S_;
  float xc=cb[h];
#pragma unroll
  for(int w=0;w<4;w++){
    const int sr=s-3+w;
    if(sr>=0) xc+=xin[(size_t)(b*S_+sr)*H2_+h]*ck[w*H_+h];
  }
  act[(size_t)bs*H_+h]=siluf(xc);
}

// ---- headwise q/k/v ----
__global__ __launch_bounds__(256) void qkv_k(const float* __restrict__ act,
                                             const float* __restrict__ xin,
                                             const float* __restrict__ Wq,
                                             const float* __restrict__ Wk,
                                             const float* __restrict__ Wv,
                                             float* __restrict__ qb,float* __restrict__ kb,
                                             float* __restrict__ vb){
  const int i=blockIdx.x*256+threadIdx.x;
  if(i>=(int)N_BSH) return;
  const int bs=i/H_, h=i-bs*H_;
  const int b=bs/S_, s=bs-b*S_;
  const int ph=h>>2, o=h&3, base=ph*4;
  float q=0.f,k=0.f,v=0.f;
#pragma unroll
  for(int d=0;d<4;d++){
    const float a=act[(size_t)bs*H_+base+d];
    const float x=xin[(size_t)bs*H2_+base+d];
    q+=a*Wq[ph*16+d*4+o];
    k+=a*Wk[ph*16+d*4+o];
    v+=x*Wv[ph*16+d*4+o];
  }
  const int nh=h/DH_, dh=h-nh*DH_;
  const size_t off=((size_t)(b*NH_+nh)*S_+s)*DH_+dh;
  qb[off]=q; kb[off]=k; vb[off]=v;
}

// ---- gate pre-activations (round-4, passing) ----
__global__ __launch_bounds__(256) void gates_k(const float* __restrict__ qb,
                                               const float* __restrict__ kb,
                                               const float* __restrict__ vb,
                                               const float* __restrict__ Wig,
                                               const float* __restrict__ big,
                                               const float* __restrict__ Wfg,
                                               const float* __restrict__ bfg,
                                               float* __restrict__ igb,float* __restrict__ logfb){
  const int i=blockIdx.x*256+threadIdx.x;
  if(i>=BS_*NH_) return;
  const int bs=i>>2, n=i&3;
  const int b=bs/S_, s=bs-b*S_;
  float sig=0.f,sfg=0.f;
  for(int nh=0;nh<NH_;nh++){
    const size_t rb=((size_t)(b*NH_+nh)*S_+s)*DH_;
    for(int dh=0;dh<DH_;dh++){
      const int h=nh*DH_+dh;
      const float q=qb[rb+dh], k=kb[rb+dh], v=vb[rb+dh];
      sig+=q*Wig[h*4+n]+k*Wig[(H_+h)*4+n]+v*Wig[(2*H_+h)*4+n];
      sfg+=q*Wfg[h*4+n]+k*Wfg[(H_+h)*4+n]+v*Wfg[(2*H_+h)*4+n];
    }
  }
  const size_t off=(size_t)(b*NH_+n)*S_+s;
  igb[off]=sig+big[n];
  logfb[off]=logsigf(sfg+bfg[n]);
}

// ---- K prep: split fp32 K into hi/lo bf16, MFMA B-fragment tile layout ----
__global__ __launch_bounds__(256) void kprep_k(const float* __restrict__ kb,
                                               unsigned short* __restrict__ khi,
                                               unsigned short* __restrict__ klo){
  const int blk=blockIdx.x;                 // 8 heads * 128 t-tiles
  const int head=blk>>7, tt=blk&127;
  const size_t obase=(size_t)blk*11*512;
  for(int slot=threadIdx.x; slot<704; slot+=256){
    const int dc=slot>>6, ll=slot&63, quad=ll>>4, lm=ll&15;
    const int tg=tt*16+lm, dbase=dc*32+quad*8;
    float v[8];
    if(dbase<336){
      load4(&kb[((size_t)head*S_+tg)*DH_+dbase],v);
      load4(&kb[((size_t)head*S_+tg)*DH_+dbase+4],v+4);
    } else { for(int j=0;j<8;j++) v[j]=0.f; }
    unsigned short hi8[8], lo8[8];
#pragma unroll
    for(int j=0;j<8;j++){
      hi8[j]=f2bf(v[j]);
      lo8[j]=f2bf(v[j]-bf2f(hi8[j]));
    }
    const size_t o=obase+(size_t)(dc*64+ll)*8;
    uint4 ph, pl;
    ph.x=(unsigned)hi8[0]|((unsigned)hi8[1]<<16); ph.y=(unsigned)hi8[2]|((unsigned)hi8[3]<<16);
    ph.z=(unsigned)hi8[4]|((unsigned)hi8[5]<<16); ph.w=(unsigned)hi8[6]|((unsigned)hi8[7]<<16);
    pl.x=(unsigned)lo8[0]|((unsigned)lo8[1]<<16); pl.y=(unsigned)lo8[2]|((unsigned)lo8[3]<<16);
    pl.z=(unsigned)lo8[4]|((unsigned)lo8[5]<<16); pl.w=(unsigned)lo8[6]|((unsigned)lo8[7]<<16);
    *reinterpret_cast<uint4*>(&khi[o])=ph;
    *reinterpret_cast<uint4*>(&klo[o])=pl;
  }
}

// ---- V prep: V^T bf16 in MFMA B-fragment tile layout; col 336 = ones ----
__global__ __launch_bounds__(256) void vprep_k(const float* __restrict__ vb,
                                               unsigned short* __restrict__ vTf){
  const int blk=blockIdx.x;                 // 8 heads * 64 t-chunks
  const int head=blk>>6, tc=blk&63;
  const size_t obase=(size_t)blk*22*512;
  for(int slot=threadIdx.x; slot<1408; slot+=256){
    const int ntg=slot>>6, ll=slot&63, quad=ll>>4, lm=ll&15;
    const int n=ntg*16+lm, t0=tc*32+quad*8;
    unsigned short h8[8];
#pragma unroll
    for(int j=0;j<8;j++){
      float val;
      if(n<336)       val=vb[((size_t)head*S_+t0+j)*DH_+n];
      else if(n==336) val=1.f;
      else            val=0.f;
      h8[j]=f2bf(val);
    }
    uint4 pk;
    pk.x=(unsigned)h8[0]|((unsigned)h8[1]<<16); pk.y=(unsigned)h8[2]|((unsigned)h8[3]<<16);
    pk.z=(unsigned)h8[4]|((unsigned)h8[5]<<16); pk.w=(unsigned)h8[6]|((unsigned)h8[7]<<16);
    *reinterpret_cast<uint4*>(&vTf[obase+(size_t)(ntg*64+ll)*8])=pk;
  }
}

// ---- parallel per-head scan (rounds 7-9, passing) ----
__global__ __launch_bounds__(256) void scan_k(const float* __restrict__ igb,
                                              const float* __restrict__ logfb,
                                              float* __restrict__ ab,float* __restrict__ Mb,
                                              float* __restrict__ mtb){
  const int head=blockIdx.x, t=threadIdx.x;
  __shared__ float sh[256];
  const float* lf=logfb+(size_t)head*S_;
  const float* ig=igb+(size_t)head*S_;
  float lc[8];
  float run=0.f;
#pragma unroll
  for(int i=0;i<8;i++){ run+=lf[t*8+i]; lc[i]=run; }
  sh[t]=run;
  for(int st=1;st<256;st<<=1){
    __syncthreads();
    const float v=(t>=st)?sh[t-st]:0.f;
    __syncthreads();
    sh[t]+=v;
  }
  __syncthreads();
  const float off=(t==0)?0.f:sh[t-1];
  __syncthreads();
  float av[8],mv[8],cv[8];
  float mrun=-1e30f;
#pragma unroll
  for(int i=0;i<8;i++){
    cv[i]=off+lc[i];
    av[i]=ig[t*8+i]-cv[i];
    mrun=fmaxf(mrun,av[i]);
    mv[i]=mrun;
  }
  sh[t]=mrun;
  for(int st=1;st<256;st<<=1){
    __syncthreads();
    const float v=(t>=st)?sh[t-st]:-1e30f;
    __syncthreads();
    sh[t]=fmaxf(sh[t],v);
  }
  __syncthreads();
  const float moff=(t==0)?-1e30f:sh[t-1];
#pragma unroll
  for(int i=0;i<8;i++){
    const float Mi=fmaxf(moff,mv[i]);
    const size_t j=(size_t)head*S_+t*8+i;
    ab[j]=av[i]; Mb[j]=Mi; mtb[j]=cv[i]+Mi;
  }
}

// ============================================================================
// mLSTM v6 (round-9, passing) — 64-row supertiles, barrier-free, XCD-pinned.
// ============================================================================
__global__ __launch_bounds__(256) void mlstm_k(
    const float* __restrict__ qb, const unsigned short* __restrict__ khi,
    const unsigned short* __restrict__ klo, const unsigned short* __restrict__ vTf,
    const float* __restrict__ ab, const float* __restrict__ Mb,
    float* __restrict__ part, float* __restrict__ rsum){
  const int bid=blockIdx.x;
  const int head=bid&7;                       // XCD-pin heuristic
  const int r2=bid>>3;
  const int seg=r2&3;
  const int sb=31-(r2>>2);                    // heavy supertiles first
  const int s0=sb*64;
  const int nch=2*sb+2;
  if(seg>=nch) return;
  const int t=threadIdx.x, w=t>>6, l=t&63, lm=l&15, quad=l>>4;
  const int ws0=s0+w*16;

  __shared__ short Sc[4][16][40];             // per-wave buffers; no barriers

  const size_t hb=(size_t)head*S_;
  bf16x8 qh[11], ql[11];
  {
    const float* qrow=qb+(hb+ws0+lm)*DH_;
#pragma unroll
    for(int dc=0;dc<11;dc++){
      const int dbase=dc*32+quad*8;
      float v[8];
      if(dbase<336){ load4(qrow+dbase,v); load4(qrow+dbase+4,v+4); }
      else { for(int j=0;j<8;j++) v[j]=0.f; }
#pragma unroll
      for(int j=0;j<8;j++){
        const unsigned short h=f2bf(v[j]);
        qh[dc][j]=(short)h;
        ql[dc][j]=(short)f2bf(v[j]-bf2f(h));
      }
    }
  }
  float Mr[4];
#pragma unroll
  for(int r=0;r<4;r++) Mr[r]=Mb[hb+ws0+quad*4+r];

  f32x4 accO[22];
#pragma unroll
  for(int n=0;n<22;n++) accO[n]={0.f,0.f,0.f,0.f};

  const float scale=0.05455447256f;           // 336^-0.5

  for(int c=seg;c<nch;c+=TS_){
    const int t0=c<<5;
    const float al0=ab[hb+t0+lm];
    const float al1=ab[hb+t0+16+lm];
#pragma unroll
    for(int tt=0;tt<2;tt++){
      const size_t kb0=(((size_t)head*128+(size_t)(c*2+tt))*11)*512+(size_t)l*8;
      f32x4 a0={0,0,0,0}, a1={0,0,0,0}, a2={0,0,0,0};
#pragma unroll
      for(int dc=0;dc<11;dc++){
        const bf16x8 kh=*reinterpret_cast<const bf16x8*>(&khi[kb0+(size_t)dc*512]);
        const bf16x8 kl=*reinterpret_cast<const bf16x8*>(&klo[kb0+(size_t)dc*512]);
        a0=__builtin_amdgcn_mfma_f32_16x16x32_bf16(qh[dc],kh,a0,0,0,0);
        a1=__builtin_amdgcn_mfma_f32_16x16x32_bf16(ql[dc],kh,a1,0,0,0);
        a2=__builtin_amdgcn_mfma_f32_16x16x32_bf16(qh[dc],kl,a2,0,0,0);
      }
      const float al=(tt==0)?al0:al1;
      const int tg=t0+tt*16+lm;
#pragma unroll
      for(int r=0;r<4;r++){
        const int srow=quad*4+r;
        const float qk=a0[r]+a1[r]+a2[r];
        const float e=fminf(al-Mr[r],0.f);
        const float msk=(tg<=ws0+srow)?1.f:0.f;
        Sc[w][srow][tt*16+lm]=(short)f2bf(msk*(qk*scale*expf(e)));
      }
    }
    const bf16x8 scf=*reinterpret_cast<const bf16x8*>(&Sc[w][lm][quad*8]);
    const size_t vb0=(((size_t)head*64+c)*22)*512+(size_t)l*8;
#pragma unroll
    for(int nt=0;nt<22;nt++){
      const bf16x8 vf=*reinterpret_cast<const bf16x8*>(&vTf[vb0+(size_t)nt*512]);
      accO[nt]=__builtin_amdgcn_mfma_f32_16x16x32_bf16(scf,vf,accO[nt],0,0,0);
    }
  }

  const size_t pbase=(size_t)head*2048+ws0;
#pragma unroll
  for(int nt=0;nt<22;nt++){
    const int col=nt*16+lm;
#pragma unroll
    for(int r=0;r<4;r++){
      const int srow=quad*4+r;
      const float val=accO[nt][r];
      if(col<336){ if(val!=0.f) atomicAdd(&part[(pbase+srow)*336+col],val); }
      else if(col==336){ if(val!=0.f) atomicAdd(&rsum[pbase+srow],val); }
    }
  }
}

// ============================================================================
// finalize: n-normalizer + per-head groupnorm + hout write.
// ============================================================================
__global__ __launch_bounds__(256) void finalize_k(const float* __restrict__ part,
                                                  const float* __restrict__ rsum,
                                                  const float* __restrict__ mtb,
                                                  const float* __restrict__ lnw,
                                                  float* __restrict__ hout){
  const int sblk=blockIdx.x, head=blockIdx.y;
  const int bI=head>>2, nh=head&3;
  const int s0=sblk*32;
  const int t=threadIdx.x, row=t>>3, sub=t&7;
  __shared__ float red1[32][8], red2[32][8];
  __shared__ float mu_s[32], rs_s[32], inv_s[32];
  const size_t pbase=(size_t)head*2048+s0;
  const float* prow=part+(pbase+row)*336;
  float s1=0.f,s2=0.f;
  for(int c=sub;c<336;c+=8){ const float v=prow[c]; s1+=v; s2+=v*v; }
  red1[row][sub]=s1; red2[row][sub]=s2;
  __syncthreads();
  if(sub==0){
    float a1=0.f,a2=0.f;
#pragma unroll
    for(int j=0;j<8;j++){ a1+=red1[row][j]; a2+=red2[row][j]; }
    const float mt=mtb[(size_t)head*S_+s0+row];
    const float nn=fmaxf(fabsf(rsum[pbase+row]), expf(fminf(fmaxf(-mt,-60.f),60.f)));
    const float inv=1.f/(nn+1e-6f);
    const float mu=a1*inv/336.f;
    const float var=a2*inv*inv/336.f-mu*mu;
    inv_s[row]=inv; mu_s[row]=mu;
    rs_s[row]=rsqrtf(fmaxf(var,0.f)+1e-5f);
  }
  __syncthreads();
  const float inv=inv_s[row], mu=mu_s[row], rs=rs_s[row];
  float* orow=hout+((size_t)(bI*S_+s0+row))*H_+nh*DH_;
  for(int c=sub;c<336;c+=8)
    orow[c]=(prow[c]*inv-mu)*rs*lnw[nh*DH_+c];
}

// ---- h_state = (h_out + skip*act) * silu(z) ----
__global__ __launch_bounds__(256) void hstate_k(const float* __restrict__ hout,
                                                const float* __restrict__ act,
                                                const float* __restrict__ xin,
                                                const float* __restrict__ skip,
                                                float* __restrict__ hs){
  const int i=blockIdx.x*256+threadIdx.x;
  if(i>=(int)N_BSH) return;
  const int bs=i/H_, h=i-bs*H_;
  const float z=xin[(size_t)bs*H2_+H_+h];
  hs[(size_t)bs*H_+h]=(hout[(size_t)bs*H_+h]+skip[h]*act[(size_t)bs*H_+h])*siluf(z);
}

// ============================================================================
extern "C" void kernel_launch(void* const* d_in, const int* in_sizes, int n_in,
                              void* d_out, int out_size, void* d_ws, size_t ws_size,
                              hipStream_t stream){
  float* ws=(float*)d_ws;
  int* flag=(int*)ws;

  float* igb  = ws+O_IGB;
  float* logfb= ws+O_LOGF;
  float* ab   = ws+O_AB;
  float* Mbuf = ws+O_MB;
  float* mtb  = ws+O_MTB;
  float* f_ck = ws+O_CK;
  float* f_cb = ws+O_CB;
  float* f_wq = ws+O_WQ;
  float* f_wk = ws+O_WK;
  float* f_wv = ws+O_WV;
  float* f_wig= ws+O_WIG;
  float* f_big= ws+O_BIG;
  float* f_wfg= ws+O_WFG;
  float* f_bfg= ws+O_BFG;
  float* f_lnw= ws+O_LNW;
  float* f_skp= ws+O_SKP;
  float* xin  = ws+O_XIN;
  float* act  = ws+O_ACT;
  float* qb   = ws+O_QB;
  float* kb   = ws+O_KB;
  float* vb   = ws+O_VB;
  float* hout = ws+O_HOUT;
  float* hs   = qb;                            // alias: q dead after mlstm_k

  // x/Wup/Wdn fragment buffers replace their fp32 copies (byte-identical regions)
  unsigned short* xhi  =(unsigned short*)(ws+O_FX);   unsigned short* xlo  =xhi+N_X;
  unsigned short* wuphi=(unsigned short*)(ws+O_FWUP); unsigned short* wuplo=wuphi+N_WUP;
  unsigned short* wdnhi=(unsigned short*)(ws+O_FWDN); unsigned short* wdnlo=wdnhi+N_WDN;
  // khi/klo alias x+wup frag region (dead after up-gemm); hs frags alias kb
  unsigned short* khi=(unsigned short*)(ws+O_FX);
  unsigned short* klo=khi+KSPLIT_SHORTS;
  unsigned short* vTf=(unsigned short*)kb;     // kb dead after gates+kprep
  unsigned short* hshi=(unsigned short*)kb;    // vTf dead after mlstm_k
  unsigned short* hslo=hshi+N_BSH;
  float* partb=vb;                             // vb dead after vprep
  float* rsumb=igb;                            // igb dead after scan_k

  detect_k<<<1,256,0,stream>>>((const unsigned short*)d_in[0],flag);
  auto cvt=[&](int idx,float* dst,size_t n){
    convert_k<<<(int)((n+255)/256),256,0,stream>>>(d_in[idx],dst,(int)n,flag);
  };
  cvt(2,f_ck,N_CK);  cvt(3,f_cb,H_);
  cvt(4,f_wq,N_WH); cvt(5,f_wk,N_WH);   cvt(6,f_wv,N_WH);  cvt(7,f_wig,N_WG);
  cvt(8,f_big,4);   cvt(9,f_wfg,N_WG);  cvt(10,f_bfg,4);   cvt(11,f_lnw,H_);
  cvt(12,f_skp,H_);

  // up-GEMM: xin = x @ Wup  (M=4096,K=1024 kcn=32, N=2688)
  aprep_k<<<(256*32*64+255)/256,256,0,stream>>>(d_in[0],flag,32,1024,256*32*64,xhi,xlo);
  bprep_k<<<(168*32*64+255)/256,256,0,stream>>>(d_in[1],flag,32,2688,168*32*64,wuphi,wuplo);
  gemm_mfma_k<<<dim3(2688/64,4096/128),256,0,stream>>>(xhi,xlo,wuphi,wuplo,xin,nullptr,32,H2_);

  conv_act_k<<<(int)((N_BSH+255)/256),256,0,stream>>>(xin,f_ck,f_cb,act);
  qkv_k<<<(int)((N_BSH+255)/256),256,0,stream>>>(act,xin,f_wq,f_wk,f_wv,qb,kb,vb);
  gates_k<<<(BS_*NH_+255)/256,256,0,stream>>>(qb,kb,vb,f_wig,f_big,f_wfg,f_bfg,igb,logfb);
  kprep_k<<<8*128,256,0,stream>>>(kb,khi,klo);
  vprep_k<<<8*64,256,0,stream>>>(vb,vTf);
  // wdn frags (independent; region untouched by khi/klo)
  bprep_k<<<(64*42*64+255)/256,256,0,stream>>>(d_in[13],flag,42,1024,64*42*64,wdnhi,wdnlo);
  scan_k<<<B_*NH_,256,0,stream>>>(igb,logfb,ab,Mbuf,mtb);
  hipMemsetAsync(partb,0,N_BSH*sizeof(float),stream);
  hipMemsetAsync(rsumb,0,(size_t)NG_*sizeof(float),stream);
  mlstm_k<<<1024,256,0,stream>>>(qb,khi,klo,vTf,ab,Mbuf,partb,rsumb);
  finalize_k<<<dim3(S_/32,B_*NH_),256,0,stream>>>(partb,rsumb,mtb,f_lnw,hout);
  hstate_k<<<(int)((N_BSH+255)/256),256,0,stream>>>(hout,act,xin,f_skp,hs);
  // down-GEMM: out = hs @ Wdn  (M=4096,K=1344 kcn=42, N=1024), direct to d_out
  aprep_k<<<(256*42*64+255)/256,256,0,stream>>>(hs,nullptr,42,1344,256*42*64,hshi,hslo);
  gemm_mfma_k<<<dim3(1024/64,4096/128),256,0,stream>>>(hshi,hslo,wdnhi,wdnlo,d_out,flag,42,E_);
}